// Round 1
// baseline (347.882 us; speedup 1.0000x reference)
//
#include <hip/hip_runtime.h>
#include <stdint.h>

#define HIDDEN 1024
#define HEADS  16
#define DK     64
#define BATCH  2
#define SEQ    2048
#define MTOT   (BATCH*SEQ)

typedef float  f32x4  __attribute__((ext_vector_type(4)));
typedef __bf16 bf16x8 __attribute__((ext_vector_type(8)));

__device__ __forceinline__ unsigned short f2bf(float f) {
    union { float f; uint32_t u; } x;
    x.f = f;
    uint32_t r = x.u + 0x7fffu + ((x.u >> 16) & 1u);
    return (unsigned short)(r >> 16);
}

__device__ __forceinline__ bf16x8 ld_bf8(const unsigned short* p) {
    return *reinterpret_cast<const bf16x8*>(p);
}

__device__ __forceinline__ void gload16(const void* g, void* l) {
    __builtin_amdgcn_global_load_lds(
        (const __attribute__((address_space(1))) void*)g,
        (__attribute__((address_space(3))) void*)l, 16, 0, 0);
}

// ---------------- fp32 -> bf16 convert, 8 elems/thread ----------------
__global__ __launch_bounds__(256) void cvt_kernel(const float* __restrict__ src,
                                                  unsigned short* __restrict__ dst,
                                                  int n8) {
    int i = blockIdx.x * blockDim.x + threadIdx.x;
    if (i >= n8) return;
    const float4* s = reinterpret_cast<const float4*>(src) + (size_t)i * 2;
    float4 a = s[0], b = s[1];
    union { unsigned short us[8]; uint4 v; } o;
    o.us[0] = f2bf(a.x); o.us[1] = f2bf(a.y); o.us[2] = f2bf(a.z); o.us[3] = f2bf(a.w);
    o.us[4] = f2bf(b.x); o.us[5] = f2bf(b.y); o.us[6] = f2bf(b.z); o.us[7] = f2bf(b.w);
    reinterpret_cast<uint4*>(dst)[i] = o.v;
}

// ---------------- GEMM body: C[M,N] = A[M,K]bf16 * W[N,K]^T bf16 + bias ----------------
// mode 0: bf16 out, [B,H,S,DK] scatter     (q,k projections)
// mode 1: bf16 out, [B,H,DK,S] scatter     (v projection, transposed)
// mode 2: f32  out, row-major [M,N]        (final projection)
__device__ __forceinline__ void gemm_body(const unsigned short* __restrict__ A,
                                          const unsigned short* __restrict__ W,
                                          const float* __restrict__ bias,
                                          void* __restrict__ out, int mode) {
    __shared__ __align__(16) unsigned short Alds[128 * 64];
    __shared__ __align__(16) unsigned short Blds[128 * 64];
    const int t    = threadIdx.x;
    const int lane = t & 63;
    const int wid  = t >> 6;
    const int wm   = (wid >> 1) * 64;
    const int wn   = (wid & 1) * 64;
    const int fr   = lane & 15;
    const int fg   = lane >> 4;
    const int bm   = blockIdx.y, bn = blockIdx.x;
    const int K    = HIDDEN;

    f32x4 acc[4][4];
#pragma unroll
    for (int i = 0; i < 4; i++)
#pragma unroll
        for (int j = 0; j < 4; j++) acc[i][j] = (f32x4){0.f, 0.f, 0.f, 0.f};

    const int seg_row = t >> 3;       // 0..31 per iter
    const int seg_col = (t & 7) * 8;  // bf16 col offset

    for (int k0 = 0; k0 < K; k0 += 64) {
#pragma unroll
        for (int i = 0; i < 4; i++) {
            int row = i * 32 + seg_row;
            const unsigned short* ga = A + (size_t)(bm * 128 + row) * K + k0 + seg_col;
            const unsigned short* gb = W + (size_t)(bn * 128 + row) * K + k0 + seg_col;
            unsigned short* la = Alds + (size_t)(i * 256 + (t & ~63)) * 8;
            unsigned short* lb = Blds + (size_t)(i * 256 + (t & ~63)) * 8;
            gload16(ga, la);
            gload16(gb, lb);
        }
        __syncthreads();
#pragma unroll
        for (int kk = 0; kk < 2; kk++) {
            bf16x8 af[4], bf[4];
#pragma unroll
            for (int mt = 0; mt < 4; mt++)
                af[mt] = ld_bf8(&Alds[(wm + mt * 16 + fr) * 64 + kk * 32 + fg * 8]);
#pragma unroll
            for (int nt = 0; nt < 4; nt++)
                bf[nt] = ld_bf8(&Blds[(wn + nt * 16 + fr) * 64 + kk * 32 + fg * 8]);
#pragma unroll
            for (int mt = 0; mt < 4; mt++)
#pragma unroll
                for (int nt = 0; nt < 4; nt++)
                    acc[mt][nt] = __builtin_amdgcn_mfma_f32_16x16x32_bf16(
                        af[mt], bf[nt], acc[mt][nt], 0, 0, 0);
        }
        __syncthreads();
    }

    const int base_row = bm * 128 + wm + fg * 4;
    const int base_col = bn * 128 + wn + fr;
#pragma unroll
    for (int mt = 0; mt < 4; mt++) {
#pragma unroll
        for (int nt = 0; nt < 4; nt++) {
            int col = base_col + nt * 16;
            float bv = bias[col];
#pragma unroll
            for (int e = 0; e < 4; e++) {
                int row = base_row + mt * 16 + e;
                float val = acc[mt][nt][e] + bv;
                if (mode == 2) {
                    ((float*)out)[(size_t)row * HIDDEN + col] = val;
                } else {
                    int b = row >> 11, s = row & (SEQ - 1);
                    int h = col >> 6, d = col & (DK - 1);
                    size_t idx;
                    if (mode == 0)
                        idx = ((size_t)(b * HEADS + h) * SEQ + s) * DK + d;
                    else
                        idx = ((size_t)(b * HEADS + h) * DK + d) * SEQ + s;
                    ((unsigned short*)out)[idx] = f2bf(val);
                }
            }
        }
    }
}

__global__ __launch_bounds__(256) void gemm_qkv(
    const unsigned short* __restrict__ qbf, const unsigned short* __restrict__ kbf,
    const unsigned short* __restrict__ vbf, const unsigned short* __restrict__ wq,
    const unsigned short* __restrict__ wk, const unsigned short* __restrict__ wv,
    const float* __restrict__ bq, const float* __restrict__ bk,
    const float* __restrict__ bv, unsigned short* __restrict__ qh,
    unsigned short* __restrict__ kh, unsigned short* __restrict__ vt) {
    int z = blockIdx.z;
    const unsigned short* A = (z == 0) ? qbf : (z == 1) ? kbf : vbf;
    const unsigned short* W = (z == 0) ? wq : (z == 1) ? wk : wv;
    const float* bias       = (z == 0) ? bq : (z == 1) ? bk : bv;
    unsigned short* out     = (z == 0) ? qh : (z == 1) ? kh : vt;
    gemm_body(A, W, bias, out, (z == 2) ? 1 : 0);
}

__global__ __launch_bounds__(256) void gemm_out(const unsigned short* __restrict__ ctx,
                                                const unsigned short* __restrict__ wo,
                                                const float* __restrict__ bo,
                                                float* __restrict__ out) {
    gemm_body(ctx, wo, bo, out, 2);
}

// ---------------- flash attention ----------------
// grid: (SEQ/64, BATCH*HEADS), block 256 (4 waves x 16 q-rows)
// qh, kh: [B*H, S, DK] bf16.  vt: [B*H, DK, S] bf16.  ctx: [B, S, H*DK] bf16.
__global__ __launch_bounds__(256) void attn_kernel(const unsigned short* __restrict__ qh,
                                                   const unsigned short* __restrict__ kh,
                                                   const unsigned short* __restrict__ vt,
                                                   unsigned short* __restrict__ ctx) {
    const int t = threadIdx.x, lane = t & 63, w = t >> 6;
    const int fr = lane & 15, fg = lane >> 4;
    const int bx = blockIdx.x, by = blockIdx.y;
    const size_t hb = (size_t)by * (SEQ * DK);
    const int q0 = bx * 64 + w * 16;

    __shared__ __align__(16) unsigned short Pb[4][16][40];  // +8 pad breaks conflicts

    // Q fragments, held all kernel
    bf16x8 aq[2];
#pragma unroll
    for (int kk = 0; kk < 2; kk++)
        aq[kk] = ld_bf8(&qh[hb + (size_t)(q0 + fr) * DK + kk * 32 + fg * 8]);

    f32x4 o[4];
#pragma unroll
    for (int i = 0; i < 4; i++) o[i] = (f32x4){0.f, 0.f, 0.f, 0.f};
    float mrow[4] = {-3.0e38f, -3.0e38f, -3.0e38f, -3.0e38f};
    float lrow[4] = {0.f, 0.f, 0.f, 0.f};

    for (int k0 = 0; k0 < SEQ; k0 += 32) {
        // S = Q K^T for 32 keys: two 16x16 col-tiles
        f32x4 s0 = (f32x4){0.f, 0.f, 0.f, 0.f};
        f32x4 s1 = (f32x4){0.f, 0.f, 0.f, 0.f};
#pragma unroll
        for (int kk = 0; kk < 2; kk++) {
            bf16x8 b0 = ld_bf8(&kh[hb + (size_t)(k0 + fr) * DK + kk * 32 + fg * 8]);
            bf16x8 b1 = ld_bf8(&kh[hb + (size_t)(k0 + 16 + fr) * DK + kk * 32 + fg * 8]);
            s0 = __builtin_amdgcn_mfma_f32_16x16x32_bf16(aq[kk], b0, s0, 0, 0, 0);
            s1 = __builtin_amdgcn_mfma_f32_16x16x32_bf16(aq[kk], b1, s1, 0, 0, 0);
        }
        // online softmax, wave-parallel: rows live in 16-lane groups (same fg)
        float fac[4];
#pragma unroll
        for (int e = 0; e < 4; e++) {
            float v0 = s0[e] * 0.125f;
            float v1 = s1[e] * 0.125f;
            float mx = fmaxf(v0, v1);
#pragma unroll
            for (int off = 1; off < 16; off <<= 1) mx = fmaxf(mx, __shfl_xor(mx, off));
            float mn = fmaxf(mrow[e], mx);
            fac[e] = __expf(mrow[e] - mn);
            float p0 = __expf(v0 - mn);
            float p1 = __expf(v1 - mn);
            float sm = p0 + p1;
#pragma unroll
            for (int off = 1; off < 16; off <<= 1) sm += __shfl_xor(sm, off);
            lrow[e] = lrow[e] * fac[e] + sm;
            mrow[e] = mn;
            Pb[w][fg * 4 + e][fr]      = f2bf(p0);
            Pb[w][fg * 4 + e][16 + fr] = f2bf(p1);
        }
#pragma unroll
        for (int t4 = 0; t4 < 4; t4++)
#pragma unroll
            for (int e = 0; e < 4; e++) o[t4][e] *= fac[e];
        // P fragment (A-layout): row=fr, k=fg*8..+8
        bf16x8 ap = ld_bf8(&Pb[w][fr][fg * 8]);
        // PV: O[16,64] += P[16,32] * V[32,64]; V^T stored so B-frag is contiguous
#pragma unroll
        for (int t4 = 0; t4 < 4; t4++) {
            bf16x8 bv = ld_bf8(&vt[hb + (size_t)(t4 * 16 + fr) * SEQ + k0 + fg * 8]);
            o[t4] = __builtin_amdgcn_mfma_f32_16x16x32_bf16(ap, bv, o[t4], 0, 0, 0);
        }
    }

    const int b = by >> 4, h = by & (HEADS - 1);
#pragma unroll
    for (int t4 = 0; t4 < 4; t4++) {
#pragma unroll
        for (int e = 0; e < 4; e++) {
            int srow = q0 + fg * 4 + e;
            float val = o[t4][e] / lrow[e];
            ctx[((size_t)(b * SEQ + srow)) * HIDDEN + h * 64 + t4 * 16 + fr] = f2bf(val);
        }
    }
}

// ---------------- launch ----------------
extern "C" void kernel_launch(void* const* d_in, const int* in_sizes, int n_in,
                              void* d_out, int out_size, void* d_ws, size_t ws_size,
                              hipStream_t stream) {
    const float* q  = (const float*)d_in[0];
    const float* k  = (const float*)d_in[1];
    const float* v  = (const float*)d_in[2];
    const float* Wq = (const float*)d_in[3];
    const float* bq = (const float*)d_in[4];
    const float* Wk = (const float*)d_in[5];
    const float* bk = (const float*)d_in[6];
    const float* Wv = (const float*)d_in[7];
    const float* bv = (const float*)d_in[8];
    const float* Wo = (const float*)d_in[9];
    const float* bo = (const float*)d_in[10];

    unsigned short* qbf = (unsigned short*)d_ws;
    unsigned short* kbf = qbf + (size_t)MTOT * HIDDEN;
    unsigned short* vbf = kbf + (size_t)MTOT * HIDDEN;
    unsigned short* wqb = vbf + (size_t)MTOT * HIDDEN;
    unsigned short* wkb = wqb + (size_t)HIDDEN * HIDDEN;
    unsigned short* wvb = wkb + (size_t)HIDDEN * HIDDEN;
    unsigned short* wob = wvb + (size_t)HIDDEN * HIDDEN;
    unsigned short* qh  = wob + (size_t)HIDDEN * HIDDEN;
    unsigned short* kh  = qh + (size_t)MTOT * HIDDEN;
    unsigned short* vt  = kh + (size_t)MTOT * HIDDEN;
    unsigned short* ctx = vt + (size_t)MTOT * HIDDEN;

    const int nAct8 = MTOT * HIDDEN / 8;    // 524288
    const int nW8   = HIDDEN * HIDDEN / 8;  // 131072

    cvt_kernel<<<dim3(nAct8 / 256), dim3(256), 0, stream>>>(q, qbf, nAct8);
    cvt_kernel<<<dim3(nAct8 / 256), dim3(256), 0, stream>>>(k, kbf, nAct8);
    cvt_kernel<<<dim3(nAct8 / 256), dim3(256), 0, stream>>>(v, vbf, nAct8);
    cvt_kernel<<<dim3(nW8 / 256), dim3(256), 0, stream>>>(Wq, wqb, nW8);
    cvt_kernel<<<dim3(nW8 / 256), dim3(256), 0, stream>>>(Wk, wkb, nW8);
    cvt_kernel<<<dim3(nW8 / 256), dim3(256), 0, stream>>>(Wv, wvb, nW8);
    cvt_kernel<<<dim3(nW8 / 256), dim3(256), 0, stream>>>(Wo, wob, nW8);

    gemm_qkv<<<dim3(HIDDEN / 128, MTOT / 128, 3), dim3(256), 0, stream>>>(
        qbf, kbf, vbf, wqb, wkb, wvb, bq, bk, bv, qh, kh, vt);

    attn_kernel<<<dim3(SEQ / 64, BATCH * HEADS), dim3(256), 0, stream>>>(qh, kh, vt, ctx);

    gemm_out<<<dim3(HIDDEN / 128, MTOT / 128), dim3(256), 0, stream>>>(
        ctx, wob, bo, (float*)d_out);
}

// Round 2
// 237.679 us; speedup vs baseline: 1.4637x; 1.4637x over previous
//
#include <hip/hip_runtime.h>
#include <stdint.h>

#define HIDDEN 1024
#define HEADS  16
#define DK     64
#define BATCH  2
#define SEQ    2048
#define MTOT   (BATCH*SEQ)
#define QSCALE 0.1803368801111204f  /* log2(e)/8 : folds softmax scale + exp2 conversion into Q */

typedef float  f32x4   __attribute__((ext_vector_type(4)));
typedef float  f32x16  __attribute__((ext_vector_type(16)));
typedef __bf16 bf16x8  __attribute__((ext_vector_type(8)));

__device__ __forceinline__ unsigned short f2bf(float f) {
    union { float f; uint32_t u; } x;
    x.f = f;
    uint32_t r = x.u + 0x7fffu + ((x.u >> 16) & 1u);
    return (unsigned short)(r >> 16);
}

__device__ __forceinline__ bf16x8 ld_bf8(const unsigned short* p) {
    return *reinterpret_cast<const bf16x8*>(p);
}

__device__ __forceinline__ void gload16(const void* g, void* l) {
    __builtin_amdgcn_global_load_lds(
        (const __attribute__((address_space(1))) void*)g,
        (__attribute__((address_space(3))) void*)l, 16, 0, 0);
}

// ---------------- fp32 -> bf16 convert, 8 elems/thread ----------------
__global__ __launch_bounds__(256) void cvt_kernel(const float* __restrict__ src,
                                                  unsigned short* __restrict__ dst,
                                                  int n8) {
    int i = blockIdx.x * blockDim.x + threadIdx.x;
    if (i >= n8) return;
    const float4* s = reinterpret_cast<const float4*>(src) + (size_t)i * 2;
    float4 a = s[0], b = s[1];
    union { unsigned short us[8]; uint4 v; } o;
    o.us[0] = f2bf(a.x); o.us[1] = f2bf(a.y); o.us[2] = f2bf(a.z); o.us[3] = f2bf(a.w);
    o.us[4] = f2bf(b.x); o.us[5] = f2bf(b.y); o.us[6] = f2bf(b.z); o.us[7] = f2bf(b.w);
    reinterpret_cast<uint4*>(dst)[i] = o.v;
}

// ---------------- GEMM body: C[M,N] = A[M,K]bf16 * W[N,K]^T bf16 + bias ----------------
// mode 0: bf16 out, [B,H,S,DK] scatter     (q,k projections; q gets QSCALE)
// mode 1: bf16 out, [B,H,DK,S] scatter     (v projection, transposed)
// mode 2: f32  out, row-major [M,N]        (final projection)
__device__ __forceinline__ void gemm_body(const unsigned short* __restrict__ A,
                                          const unsigned short* __restrict__ W,
                                          const float* __restrict__ bias,
                                          void* __restrict__ out, int mode, float scale) {
    __shared__ __align__(16) unsigned short Alds[128 * 64];
    __shared__ __align__(16) unsigned short Blds[128 * 64];
    const int t    = threadIdx.x;
    const int lane = t & 63;
    const int wid  = t >> 6;
    const int wm   = (wid >> 1) * 64;
    const int wn   = (wid & 1) * 64;
    const int fr   = lane & 15;
    const int fg   = lane >> 4;
    const int bm   = blockIdx.y, bn = blockIdx.x;
    const int K    = HIDDEN;

    f32x4 acc[4][4];
#pragma unroll
    for (int i = 0; i < 4; i++)
#pragma unroll
        for (int j = 0; j < 4; j++) acc[i][j] = (f32x4){0.f, 0.f, 0.f, 0.f};

    const int seg_row = t >> 3;       // 0..31 per iter
    const int seg_col = (t & 7) * 8;  // bf16 col offset

    for (int k0 = 0; k0 < K; k0 += 64) {
#pragma unroll
        for (int i = 0; i < 4; i++) {
            int row = i * 32 + seg_row;
            const unsigned short* ga = A + (size_t)(bm * 128 + row) * K + k0 + seg_col;
            const unsigned short* gb = W + (size_t)(bn * 128 + row) * K + k0 + seg_col;
            unsigned short* la = Alds + (size_t)(i * 256 + (t & ~63)) * 8;
            unsigned short* lb = Blds + (size_t)(i * 256 + (t & ~63)) * 8;
            gload16(ga, la);
            gload16(gb, lb);
        }
        __syncthreads();
#pragma unroll
        for (int kk = 0; kk < 2; kk++) {
            bf16x8 af[4], bf[4];
#pragma unroll
            for (int mt = 0; mt < 4; mt++)
                af[mt] = ld_bf8(&Alds[(wm + mt * 16 + fr) * 64 + kk * 32 + fg * 8]);
#pragma unroll
            for (int nt = 0; nt < 4; nt++)
                bf[nt] = ld_bf8(&Blds[(wn + nt * 16 + fr) * 64 + kk * 32 + fg * 8]);
#pragma unroll
            for (int mt = 0; mt < 4; mt++)
#pragma unroll
                for (int nt = 0; nt < 4; nt++)
                    acc[mt][nt] = __builtin_amdgcn_mfma_f32_16x16x32_bf16(
                        af[mt], bf[nt], acc[mt][nt], 0, 0, 0);
        }
        __syncthreads();
    }

    const int base_row = bm * 128 + wm + fg * 4;
    const int base_col = bn * 128 + wn + fr;
#pragma unroll
    for (int mt = 0; mt < 4; mt++) {
#pragma unroll
        for (int nt = 0; nt < 4; nt++) {
            int col = base_col + nt * 16;
            float bv = bias[col];
#pragma unroll
            for (int e = 0; e < 4; e++) {
                int row = base_row + mt * 16 + e;
                float val = (acc[mt][nt][e] + bv) * scale;
                if (mode == 2) {
                    ((float*)out)[(size_t)row * HIDDEN + col] = val;
                } else {
                    int b = row >> 11, s = row & (SEQ - 1);
                    int h = col >> 6, d = col & (DK - 1);
                    size_t idx;
                    if (mode == 0)
                        idx = ((size_t)(b * HEADS + h) * SEQ + s) * DK + d;
                    else
                        idx = ((size_t)(b * HEADS + h) * DK + d) * SEQ + s;
                    ((unsigned short*)out)[idx] = f2bf(val);
                }
            }
        }
    }
}

__global__ __launch_bounds__(256) void gemm_qkv(
    const unsigned short* __restrict__ qbf, const unsigned short* __restrict__ kbf,
    const unsigned short* __restrict__ vbf, const unsigned short* __restrict__ wq,
    const unsigned short* __restrict__ wk, const unsigned short* __restrict__ wv,
    const float* __restrict__ bq, const float* __restrict__ bk,
    const float* __restrict__ bv, unsigned short* __restrict__ qh,
    unsigned short* __restrict__ kh, unsigned short* __restrict__ vt) {
    int z = blockIdx.z;
    const unsigned short* A = (z == 0) ? qbf : (z == 1) ? kbf : vbf;
    const unsigned short* W = (z == 0) ? wq : (z == 1) ? wk : wv;
    const float* bias       = (z == 0) ? bq : (z == 1) ? bk : bv;
    unsigned short* out     = (z == 0) ? qh : (z == 1) ? kh : vt;
    gemm_body(A, W, bias, out, (z == 2) ? 1 : 0, (z == 0) ? QSCALE : 1.0f);
}

__global__ __launch_bounds__(256) void gemm_out(const unsigned short* __restrict__ ctx,
                                                const unsigned short* __restrict__ wo,
                                                const float* __restrict__ bo,
                                                float* __restrict__ out) {
    gemm_body(ctx, wo, bo, out, 2, 1.0f);
}

// ---------------- flash attention, swapped-operand 32x32 structure ----------------
// grid: 512 (XCD-chunked swizzle -> by 0..31 head-batch, bx 0..15 q-block), block 256.
// Per wave: 32 q rows, KVBLK=32, no LDS.
// qh, kh: [B*H, S, DK] bf16 (q pre-scaled by log2e/8).  vt: [B*H, DK, S] bf16.
// ctx: [B, S, H*DK] bf16.
__global__ __launch_bounds__(256) void attn_kernel(const unsigned short* __restrict__ qh,
                                                   const unsigned short* __restrict__ kh,
                                                   const unsigned short* __restrict__ vt,
                                                   unsigned short* __restrict__ ctx) {
    const int t = threadIdx.x, lane = t & 63, w = t >> 6;
    const int lo = lane & 31, hi = lane >> 5;
    const int id  = blockIdx.x;
    const int swz = (id & 7) * 64 + (id >> 3);   // XCD-chunked: 4 heads per XCD
    const int by  = swz >> 4;
    const int bx  = swz & 15;
    const size_t hb = (size_t)by * (SEQ * DK);
    const int q0 = bx * 128 + w * 32;

    // Q as B-fragments: col=q=lane&31, k=dk=tl*16+hi*8+j
    bf16x8 qf[4];
#pragma unroll
    for (int tl = 0; tl < 4; ++tl)
        qf[tl] = ld_bf8(&qh[hb + (size_t)(q0 + lo) * DK + tl * 16 + hi * 8]);

    f32x16 o0, o1;
#pragma unroll
    for (int e = 0; e < 16; ++e) { o0[e] = 0.f; o1[e] = 0.f; }
    float m = -3.0e38f, l = 0.f;

    const unsigned short* kp  = kh + hb + (size_t)lo * DK + hi * 8;
    const unsigned short* vp0 = vt + hb + (size_t)lo * SEQ + hi * 8;
    const unsigned short* vp1 = vt + hb + (size_t)(32 + lo) * SEQ + hi * 8;

    for (int k0 = 0; k0 < SEQ; k0 += 32) {
        // S^T[key, q] = K * Q^T : lane holds 16 key-rows of one q-column
        f32x16 s;
#pragma unroll
        for (int e = 0; e < 16; ++e) s[e] = 0.f;
#pragma unroll
        for (int tl = 0; tl < 4; ++tl) {
            bf16x8 kf = ld_bf8(kp + (size_t)k0 * DK + tl * 16);
            s = __builtin_amdgcn_mfma_f32_32x32x16_bf16(kf, qf[tl], s, 0, 0, 0);
        }
        // online softmax: in-lane reduce over 16 keys + one xor-32 shuffle
        float pm = s[0];
#pragma unroll
        for (int e = 1; e < 16; ++e) pm = fmaxf(pm, s[e]);
        pm = fmaxf(pm, __shfl_xor(pm, 32));
        float mn  = fmaxf(m, pm);
        float fac = __builtin_amdgcn_exp2f(m - mn);
        m = mn;
        float p[16];
        float sum = 0.f;
#pragma unroll
        for (int e = 0; e < 16; ++e) { p[e] = __builtin_amdgcn_exp2f(s[e] - mn); sum += p[e]; }
        sum += __shfl_xor(sum, 32);
        l = l * fac + sum;
#pragma unroll
        for (int e = 0; e < 16; ++e) { o0[e] *= fac; o1[e] *= fac; }
        // pack P to bf16 pairs (key order), exchange across hi-halves, build B-frags
        uint32_t w8[8], sw8[8];
#pragma unroll
        for (int i = 0; i < 8; ++i) {
            union { __bf16 h[2]; uint32_t u; } pk;
            pk.h[0] = (__bf16)p[2 * i];
            pk.h[1] = (__bf16)p[2 * i + 1];
            w8[i] = pk.u;
        }
#pragma unroll
        for (int i = 0; i < 8; ++i) sw8[i] = (uint32_t)__shfl_xor((int)w8[i], 32);
        union { uint32_t u[4]; bf16x8 v; } f0, f1;
        f0.u[0] = hi ? sw8[2] : w8[0];  f0.u[1] = hi ? sw8[3] : w8[1];
        f0.u[2] = hi ? w8[2]  : sw8[0]; f0.u[3] = hi ? w8[3]  : sw8[1];
        f1.u[0] = hi ? sw8[6] : w8[4];  f1.u[1] = hi ? sw8[7] : w8[5];
        f1.u[2] = hi ? w8[6]  : sw8[4]; f1.u[3] = hi ? w8[7]  : sw8[5];
        // O^T[d, q] += V^T * P^T
        bf16x8 v00 = ld_bf8(vp0 + k0);
        bf16x8 v01 = ld_bf8(vp0 + k0 + 16);
        bf16x8 v10 = ld_bf8(vp1 + k0);
        bf16x8 v11 = ld_bf8(vp1 + k0 + 16);
        o0 = __builtin_amdgcn_mfma_f32_32x32x16_bf16(v00, f0.v, o0, 0, 0, 0);
        o0 = __builtin_amdgcn_mfma_f32_32x32x16_bf16(v01, f1.v, o0, 0, 0, 0);
        o1 = __builtin_amdgcn_mfma_f32_32x32x16_bf16(v10, f0.v, o1, 0, 0, 0);
        o1 = __builtin_amdgcn_mfma_f32_32x32x16_bf16(v11, f1.v, o1, 0, 0, 0);
    }

    float rl = __builtin_amdgcn_rcpf(l);
    const int b = by >> 4, hd = by & 15;
    unsigned short* orow = ctx + ((size_t)(b * SEQ + q0 + lo)) * HIDDEN + hd * 64;
#pragma unroll
    for (int dt = 0; dt < 2; ++dt) {
#pragma unroll
        for (int g = 0; g < 4; ++g) {
            union { unsigned short us[4]; uint2 v; } pk;
#pragma unroll
            for (int c = 0; c < 4; ++c) {
                float val = (dt ? o1[g * 4 + c] : o0[g * 4 + c]) * rl;
                pk.us[c] = f2bf(val);
            }
            *reinterpret_cast<uint2*>(orow + dt * 32 + g * 8 + hi * 4) = pk.v;
        }
    }
}

// ---------------- launch ----------------
extern "C" void kernel_launch(void* const* d_in, const int* in_sizes, int n_in,
                              void* d_out, int out_size, void* d_ws, size_t ws_size,
                              hipStream_t stream) {
    const float* q  = (const float*)d_in[0];
    const float* k  = (const float*)d_in[1];
    const float* v  = (const float*)d_in[2];
    const float* Wq = (const float*)d_in[3];
    const float* bq = (const float*)d_in[4];
    const float* Wk = (const float*)d_in[5];
    const float* bk = (const float*)d_in[6];
    const float* Wv = (const float*)d_in[7];
    const float* bv = (const float*)d_in[8];
    const float* Wo = (const float*)d_in[9];
    const float* bo = (const float*)d_in[10];

    unsigned short* qbf = (unsigned short*)d_ws;
    unsigned short* kbf = qbf + (size_t)MTOT * HIDDEN;
    unsigned short* vbf = kbf + (size_t)MTOT * HIDDEN;
    unsigned short* wqb = vbf + (size_t)MTOT * HIDDEN;
    unsigned short* wkb = wqb + (size_t)HIDDEN * HIDDEN;
    unsigned short* wvb = wkb + (size_t)HIDDEN * HIDDEN;
    unsigned short* wob = wvb + (size_t)HIDDEN * HIDDEN;
    unsigned short* qh  = wob + (size_t)HIDDEN * HIDDEN;
    unsigned short* kh  = qh + (size_t)MTOT * HIDDEN;
    unsigned short* vt  = kh + (size_t)MTOT * HIDDEN;
    unsigned short* ctx = vt + (size_t)MTOT * HIDDEN;

    const int nAct8 = MTOT * HIDDEN / 8;    // 524288
    const int nW8   = HIDDEN * HIDDEN / 8;  // 131072

    cvt_kernel<<<dim3(nAct8 / 256), dim3(256), 0, stream>>>(q, qbf, nAct8);
    cvt_kernel<<<dim3(nAct8 / 256), dim3(256), 0, stream>>>(k, kbf, nAct8);
    cvt_kernel<<<dim3(nAct8 / 256), dim3(256), 0, stream>>>(v, vbf, nAct8);
    cvt_kernel<<<dim3(nW8 / 256), dim3(256), 0, stream>>>(Wq, wqb, nW8);
    cvt_kernel<<<dim3(nW8 / 256), dim3(256), 0, stream>>>(Wk, wkb, nW8);
    cvt_kernel<<<dim3(nW8 / 256), dim3(256), 0, stream>>>(Wv, wvb, nW8);
    cvt_kernel<<<dim3(nW8 / 256), dim3(256), 0, stream>>>(Wo, wob, nW8);

    gemm_qkv<<<dim3(HIDDEN / 128, MTOT / 128, 3), dim3(256), 0, stream>>>(
        qbf, kbf, vbf, wqb, wkb, wvb, bq, bk, bv, qh, kh, vt);

    attn_kernel<<<dim3(512), dim3(256), 0, stream>>>(qh, kh, vt, ctx);

    gemm_out<<<dim3(HIDDEN / 128, MTOT / 128), dim3(256), 0, stream>>>(
        ctx, wob, bo, (float*)d_out);
}

// Round 3
// 224.854 us; speedup vs baseline: 1.5471x; 1.0570x over previous
//
#include <hip/hip_runtime.h>
#include <stdint.h>

#define HIDDEN 1024
#define HEADS  16
#define DK     64
#define BATCH  2
#define SEQ    2048
#define MTOT   (BATCH*SEQ)
#define QSCALE 0.1803368801111204f  /* log2(e)/8 : folds softmax scale + exp2 conversion into Q */

typedef float  f32x4   __attribute__((ext_vector_type(4)));
typedef float  f32x16  __attribute__((ext_vector_type(16)));
typedef __bf16 bf16x8  __attribute__((ext_vector_type(8)));

__device__ __forceinline__ unsigned short f2bf(float f) {
    union { float f; uint32_t u; } x;
    x.f = f;
    uint32_t r = x.u + 0x7fffu + ((x.u >> 16) & 1u);
    return (unsigned short)(r >> 16);
}

__device__ __forceinline__ bf16x8 ld_bf8(const unsigned short* p) {
    return *reinterpret_cast<const bf16x8*>(p);
}

__device__ __forceinline__ void gload16(const void* g, void* l) {
    __builtin_amdgcn_global_load_lds(
        (const __attribute__((address_space(1))) void*)g,
        (__attribute__((address_space(3))) void*)l, 16, 0, 0);
}

__device__ __forceinline__ uint32_t pkbf(float a, float b) {
    union { __bf16 h[2]; uint32_t u; } pk;
    pk.h[0] = (__bf16)a; pk.h[1] = (__bf16)b;
    return pk.u;
}

// ---------------- fused fp32 -> bf16 convert for all 7 tensors ----------------
struct Cvt7 {
    const float* s[7];
    unsigned short* d[7];
    int n8[7];
};
__global__ __launch_bounds__(256) void cvt_all(Cvt7 a) {
    int id = blockIdx.y;
    int i = blockIdx.x * blockDim.x + threadIdx.x;
    if (i >= a.n8[id]) return;
    const float4* s = reinterpret_cast<const float4*>(a.s[id]) + (size_t)i * 2;
    float4 x = s[0], y = s[1];
    union { unsigned short us[8]; uint4 v; } o;
    o.us[0] = f2bf(x.x); o.us[1] = f2bf(x.y); o.us[2] = f2bf(x.z); o.us[3] = f2bf(x.w);
    o.us[4] = f2bf(y.x); o.us[5] = f2bf(y.y); o.us[6] = f2bf(y.z); o.us[7] = f2bf(y.w);
    reinterpret_cast<uint4*>(a.d[id])[i] = o.v;
}

// ---------------- GEMM body: C[M,N] = A[M,K]bf16 * W[N,K]^T bf16 + bias ----------------
// mode 0: bf16 out, [B,H,S,DK] scatter     (q,k projections; q gets QSCALE)
// mode 1: bf16 out, [B,H,DK,S] scatter     (v projection, transposed)
// mode 2: f32  out, row-major [M,N]        (final projection)
__device__ __forceinline__ void gemm_body(const unsigned short* __restrict__ A,
                                          const unsigned short* __restrict__ W,
                                          const float* __restrict__ bias,
                                          void* __restrict__ out, int mode, float scale) {
    __shared__ __align__(16) unsigned short Alds[128 * 64];
    __shared__ __align__(16) unsigned short Blds[128 * 64];
    const int t    = threadIdx.x;
    const int lane = t & 63;
    const int wid  = t >> 6;
    const int wm   = (wid >> 1) * 64;
    const int wn   = (wid & 1) * 64;
    const int fr   = lane & 15;
    const int fg   = lane >> 4;
    const int bm   = blockIdx.y, bn = blockIdx.x;
    const int K    = HIDDEN;

    f32x4 acc[4][4];
#pragma unroll
    for (int i = 0; i < 4; i++)
#pragma unroll
        for (int j = 0; j < 4; j++) acc[i][j] = (f32x4){0.f, 0.f, 0.f, 0.f};

    const int seg_row = t >> 3;       // 0..31 per iter
    const int seg_col = (t & 7) * 8;  // bf16 col offset

    for (int k0 = 0; k0 < K; k0 += 64) {
#pragma unroll
        for (int i = 0; i < 4; i++) {
            int row = i * 32 + seg_row;
            const unsigned short* ga = A + (size_t)(bm * 128 + row) * K + k0 + seg_col;
            const unsigned short* gb = W + (size_t)(bn * 128 + row) * K + k0 + seg_col;
            unsigned short* la = Alds + (size_t)(i * 256 + (t & ~63)) * 8;
            unsigned short* lb = Blds + (size_t)(i * 256 + (t & ~63)) * 8;
            gload16(ga, la);
            gload16(gb, lb);
        }
        __syncthreads();
#pragma unroll
        for (int kk = 0; kk < 2; kk++) {
            bf16x8 af[4], bf[4];
#pragma unroll
            for (int mt = 0; mt < 4; mt++)
                af[mt] = ld_bf8(&Alds[(wm + mt * 16 + fr) * 64 + kk * 32 + fg * 8]);
#pragma unroll
            for (int nt = 0; nt < 4; nt++)
                bf[nt] = ld_bf8(&Blds[(wn + nt * 16 + fr) * 64 + kk * 32 + fg * 8]);
#pragma unroll
            for (int mt = 0; mt < 4; mt++)
#pragma unroll
                for (int nt = 0; nt < 4; nt++)
                    acc[mt][nt] = __builtin_amdgcn_mfma_f32_16x16x32_bf16(
                        af[mt], bf[nt], acc[mt][nt], 0, 0, 0);
        }
        __syncthreads();
    }

    const int base_row = bm * 128 + wm + fg * 4;
    const int base_col = bn * 128 + wn + fr;
#pragma unroll
    for (int mt = 0; mt < 4; mt++) {
#pragma unroll
        for (int nt = 0; nt < 4; nt++) {
            int col = base_col + nt * 16;
            float bv = bias[col];
#pragma unroll
            for (int e = 0; e < 4; e++) {
                int row = base_row + mt * 16 + e;
                float val = (acc[mt][nt][e] + bv) * scale;
                if (mode == 2) {
                    ((float*)out)[(size_t)row * HIDDEN + col] = val;
                } else {
                    int b = row >> 11, s = row & (SEQ - 1);
                    int h = col >> 6, d = col & (DK - 1);
                    size_t idx;
                    if (mode == 0)
                        idx = ((size_t)(b * HEADS + h) * SEQ + s) * DK + d;
                    else
                        idx = ((size_t)(b * HEADS + h) * DK + d) * SEQ + s;
                    ((unsigned short*)out)[idx] = f2bf(val);
                }
            }
        }
    }
}

__global__ __launch_bounds__(256) void gemm_qkv(
    const unsigned short* __restrict__ qbf, const unsigned short* __restrict__ kbf,
    const unsigned short* __restrict__ vbf, const unsigned short* __restrict__ wq,
    const unsigned short* __restrict__ wk, const unsigned short* __restrict__ wv,
    const float* __restrict__ bq, const float* __restrict__ bk,
    const float* __restrict__ bv, unsigned short* __restrict__ qh,
    unsigned short* __restrict__ kh, unsigned short* __restrict__ vt) {
    int z = blockIdx.z;
    const unsigned short* A = (z == 0) ? qbf : (z == 1) ? kbf : vbf;
    const unsigned short* W = (z == 0) ? wq : (z == 1) ? wk : wv;
    const float* bias       = (z == 0) ? bq : (z == 1) ? bk : bv;
    unsigned short* out     = (z == 0) ? qh : (z == 1) ? kh : vt;
    gemm_body(A, W, bias, out, (z == 2) ? 1 : 0, (z == 0) ? QSCALE : 1.0f);
}

__global__ __launch_bounds__(256) void gemm_out(const unsigned short* __restrict__ ctx,
                                                const unsigned short* __restrict__ wo,
                                                const float* __restrict__ bo,
                                                float* __restrict__ out) {
    gemm_body(ctx, wo, bo, out, 2, 1.0f);
}

// ---------------- flash attention v3: in-block K-split, KVBLK=64, defer-max ----------------
// grid: 1024 blocks (XCD-chunked). block = 4 waves = 64 q-rows x 2 key-splits.
// wave w: qsub=w&1 (32 q rows), split=w>>1 (keys [split*1024, +1024)).
// Split-1 partials merged into split-0 via LDS at the end.
// qh, kh: [B*H, S, DK] bf16 (q pre-scaled by log2e/8).  vt: [B*H, DK, S] bf16.
__global__ __launch_bounds__(256, 4) void attn_kernel(const unsigned short* __restrict__ qh,
                                                      const unsigned short* __restrict__ kh,
                                                      const unsigned short* __restrict__ vt,
                                                      unsigned short* __restrict__ ctx) {
    const int t = threadIdx.x, lane = t & 63, w = t >> 6;
    const int lo = lane & 31, hi = lane >> 5;
    const int qsub = w & 1, split = w >> 1;
    const int id = blockIdx.x;
    const int g  = (id & 7) * 128 + (id >> 3);   // XCD-chunked: 4 heads per XCD
    const int by = g >> 5;                        // head-batch 0..31
    const int bx = g & 31;                        // 64-row q block 0..31
    const size_t hb = (size_t)by * (SEQ * DK);
    const int q0 = bx * 64 + qsub * 32;
    const int kbase = split * 1024;

    __shared__ float Lo[2][32][64];
    __shared__ float Lml[2][2][64];

    // Q as B-fragments: col=q=lo, k=dk
    bf16x8 qf[4];
#pragma unroll
    for (int tl = 0; tl < 4; ++tl)
        qf[tl] = ld_bf8(&qh[hb + (size_t)(q0 + lo) * DK + tl * 16 + hi * 8]);

    f32x16 o0, o1;
#pragma unroll
    for (int e = 0; e < 16; ++e) { o0[e] = 0.f; o1[e] = 0.f; }
    float m = -3.0e38f, l = 0.f;

    const unsigned short* kp  = kh + hb + (size_t)(kbase + lo) * DK + hi * 8;
    const unsigned short* vp0 = vt + hb + (size_t)lo * SEQ + kbase + hi * 8;
    const unsigned short* vp1 = vp0 + (size_t)32 * SEQ;

    for (int it = 0; it < 16; ++it) {
        const int k0 = it * 64;
        // S^T[key, q] = K * Q^T for two 32-key tiles
        f32x16 sA, sB;
#pragma unroll
        for (int e = 0; e < 16; ++e) { sA[e] = 0.f; sB[e] = 0.f; }
        __builtin_amdgcn_s_setprio(1);
#pragma unroll
        for (int tl = 0; tl < 4; ++tl) {
            bf16x8 kfA = ld_bf8(kp + (size_t)k0 * DK + tl * 16);
            bf16x8 kfB = ld_bf8(kp + (size_t)(k0 + 32) * DK + tl * 16);
            sA = __builtin_amdgcn_mfma_f32_32x32x16_bf16(kfA, qf[tl], sA, 0, 0, 0);
            sB = __builtin_amdgcn_mfma_f32_32x32x16_bf16(kfB, qf[tl], sB, 0, 0, 0);
        }
        __builtin_amdgcn_s_setprio(0);
        // online softmax over 64 keys (32 in-lane + one xor-32 shuffle)
        float pm = sA[0];
#pragma unroll
        for (int e = 1; e < 16; ++e) pm = fmaxf(pm, sA[e]);
#pragma unroll
        for (int e = 0; e < 16; ++e) pm = fmaxf(pm, sB[e]);
        pm = fmaxf(pm, __shfl_xor(pm, 32));
        // defer-max (T13): only rescale when the running max grew by > 8 (log2 units)
        if (__any(pm > m + 8.f)) {
            float mn  = fmaxf(m, pm);
            float fac = __builtin_amdgcn_exp2f(m - mn);
            m = mn;
            l *= fac;
#pragma unroll
            for (int e = 0; e < 16; ++e) { o0[e] *= fac; o1[e] *= fac; }
        }
        float sum = 0.f;
        float pA[16], pB[16];
#pragma unroll
        for (int e = 0; e < 16; ++e) {
            pA[e] = __builtin_amdgcn_exp2f(sA[e] - m);
            pB[e] = __builtin_amdgcn_exp2f(sB[e] - m);
            sum += pA[e] + pB[e];
        }
        sum += __shfl_xor(sum, 32);
        l += sum;
        // pack P to bf16 pairs; permlane32_swap yields both B-frag halves (T12)
        uint32_t pkA[8], pkB[8];
#pragma unroll
        for (int i = 0; i < 8; ++i) {
            pkA[i] = pkbf(pA[2 * i], pA[2 * i + 1]);
            pkB[i] = pkbf(pB[2 * i], pB[2 * i + 1]);
        }
        asm volatile("v_permlane32_swap_b32 %0, %1" : "+v"(pkA[0]), "+v"(pkA[2]));
        asm volatile("v_permlane32_swap_b32 %0, %1" : "+v"(pkA[1]), "+v"(pkA[3]));
        asm volatile("v_permlane32_swap_b32 %0, %1" : "+v"(pkA[4]), "+v"(pkA[6]));
        asm volatile("v_permlane32_swap_b32 %0, %1" : "+v"(pkA[5]), "+v"(pkA[7]));
        asm volatile("v_permlane32_swap_b32 %0, %1" : "+v"(pkB[0]), "+v"(pkB[2]));
        asm volatile("v_permlane32_swap_b32 %0, %1" : "+v"(pkB[1]), "+v"(pkB[3]));
        asm volatile("v_permlane32_swap_b32 %0, %1" : "+v"(pkB[4]), "+v"(pkB[6]));
        asm volatile("v_permlane32_swap_b32 %0, %1" : "+v"(pkB[5]), "+v"(pkB[7]));
        union { uint32_t u[4]; bf16x8 v; } f0, f1, f2, f3;
        f0.u[0] = pkA[0]; f0.u[1] = pkA[1]; f0.u[2] = pkA[2]; f0.u[3] = pkA[3];
        f1.u[0] = pkA[4]; f1.u[1] = pkA[5]; f1.u[2] = pkA[6]; f1.u[3] = pkA[7];
        f2.u[0] = pkB[0]; f2.u[1] = pkB[1]; f2.u[2] = pkB[2]; f2.u[3] = pkB[3];
        f3.u[0] = pkB[4]; f3.u[1] = pkB[5]; f3.u[2] = pkB[6]; f3.u[3] = pkB[7];
        // O^T[d, q] += V^T * P^T over 64 keys
        bf16x8 v00 = ld_bf8(vp0 + k0);
        bf16x8 v01 = ld_bf8(vp0 + k0 + 16);
        bf16x8 v02 = ld_bf8(vp0 + k0 + 32);
        bf16x8 v03 = ld_bf8(vp0 + k0 + 48);
        bf16x8 v10 = ld_bf8(vp1 + k0);
        bf16x8 v11 = ld_bf8(vp1 + k0 + 16);
        bf16x8 v12 = ld_bf8(vp1 + k0 + 32);
        bf16x8 v13 = ld_bf8(vp1 + k0 + 48);
        __builtin_amdgcn_s_setprio(1);
        o0 = __builtin_amdgcn_mfma_f32_32x32x16_bf16(v00, f0.v, o0, 0, 0, 0);
        o0 = __builtin_amdgcn_mfma_f32_32x32x16_bf16(v01, f1.v, o0, 0, 0, 0);
        o0 = __builtin_amdgcn_mfma_f32_32x32x16_bf16(v02, f2.v, o0, 0, 0, 0);
        o0 = __builtin_amdgcn_mfma_f32_32x32x16_bf16(v03, f3.v, o0, 0, 0, 0);
        o1 = __builtin_amdgcn_mfma_f32_32x32x16_bf16(v10, f0.v, o1, 0, 0, 0);
        o1 = __builtin_amdgcn_mfma_f32_32x32x16_bf16(v11, f1.v, o1, 0, 0, 0);
        o1 = __builtin_amdgcn_mfma_f32_32x32x16_bf16(v12, f2.v, o1, 0, 0, 0);
        o1 = __builtin_amdgcn_mfma_f32_32x32x16_bf16(v13, f3.v, o1, 0, 0, 0);
        __builtin_amdgcn_s_setprio(0);
    }

    // split-1 waves publish partials
    if (split == 1) {
#pragma unroll
        for (int e = 0; e < 16; ++e) {
            Lo[qsub][e][lane]      = o0[e];
            Lo[qsub][16 + e][lane] = o1[e];
        }
        Lml[qsub][0][lane] = m;
        Lml[qsub][1][lane] = l;
    }
    __syncthreads();
    if (split == 0) {
        float m2 = Lml[qsub][0][lane];
        float l2 = Lml[qsub][1][lane];
        float M  = fmaxf(m, m2);
        float a0 = __builtin_amdgcn_exp2f(m - M);
        float a1 = __builtin_amdgcn_exp2f(m2 - M);
        float rl = __builtin_amdgcn_rcpf(a0 * l + a1 * l2);
        const int b = by >> 4, hd = by & 15;
        unsigned short* orow = ctx + ((size_t)(b * SEQ + q0 + lo)) * HIDDEN + hd * 64;
#pragma unroll
        for (int dt = 0; dt < 2; ++dt) {
#pragma unroll
            for (int gq = 0; gq < 4; ++gq) {
                union { unsigned short us[4]; uint2 v; } pk;
#pragma unroll
                for (int c = 0; c < 4; ++c) {
                    int e = gq * 4 + c;
                    float own = dt ? o1[e] : o0[e];
                    float oth = Lo[qsub][dt * 16 + e][lane];
                    pk.us[c] = f2bf((own * a0 + oth * a1) * rl);
                }
                *reinterpret_cast<uint2*>(orow + dt * 32 + gq * 8 + hi * 4) = pk.v;
            }
        }
    }
}

// ---------------- launch ----------------
extern "C" void kernel_launch(void* const* d_in, const int* in_sizes, int n_in,
                              void* d_out, int out_size, void* d_ws, size_t ws_size,
                              hipStream_t stream) {
    const float* q  = (const float*)d_in[0];
    const float* k  = (const float*)d_in[1];
    const float* v  = (const float*)d_in[2];
    const float* Wq = (const float*)d_in[3];
    const float* bq = (const float*)d_in[4];
    const float* Wk = (const float*)d_in[5];
    const float* bk = (const float*)d_in[6];
    const float* Wv = (const float*)d_in[7];
    const float* bv = (const float*)d_in[8];
    const float* Wo = (const float*)d_in[9];
    const float* bo = (const float*)d_in[10];

    unsigned short* qbf = (unsigned short*)d_ws;
    unsigned short* kbf = qbf + (size_t)MTOT * HIDDEN;
    unsigned short* vbf = kbf + (size_t)MTOT * HIDDEN;
    unsigned short* wqb = vbf + (size_t)MTOT * HIDDEN;
    unsigned short* wkb = wqb + (size_t)HIDDEN * HIDDEN;
    unsigned short* wvb = wkb + (size_t)HIDDEN * HIDDEN;
    unsigned short* wob = wvb + (size_t)HIDDEN * HIDDEN;
    unsigned short* qh  = wob + (size_t)HIDDEN * HIDDEN;
    unsigned short* kh  = qh + (size_t)MTOT * HIDDEN;
    unsigned short* vt  = kh + (size_t)MTOT * HIDDEN;
    unsigned short* ctx = vt + (size_t)MTOT * HIDDEN;

    const int nAct8 = MTOT * HIDDEN / 8;    // 524288
    const int nW8   = HIDDEN * HIDDEN / 8;  // 131072

    Cvt7 ca;
    ca.s[0] = q;  ca.d[0] = qbf; ca.n8[0] = nAct8;
    ca.s[1] = k;  ca.d[1] = kbf; ca.n8[1] = nAct8;
    ca.s[2] = v;  ca.d[2] = vbf; ca.n8[2] = nAct8;
    ca.s[3] = Wq; ca.d[3] = wqb; ca.n8[3] = nW8;
    ca.s[4] = Wk; ca.d[4] = wkb; ca.n8[4] = nW8;
    ca.s[5] = Wv; ca.d[5] = wvb; ca.n8[5] = nW8;
    ca.s[6] = Wo; ca.d[6] = wob; ca.n8[6] = nW8;
    cvt_all<<<dim3(nAct8 / 256, 7), dim3(256), 0, stream>>>(ca);

    gemm_qkv<<<dim3(HIDDEN / 128, MTOT / 128, 3), dim3(256), 0, stream>>>(
        qbf, kbf, vbf, wqb, wkb, wvb, bq, bk, bv, qh, kh, vt);

    attn_kernel<<<dim3(1024), dim3(256), 0, stream>>>(qh, kh, vt, ctx);

    gemm_out<<<dim3(HIDDEN / 128, MTOT / 128), dim3(256), 0, stream>>>(
        ctx, wob, bo, (float*)d_out);
}

// Round 4
// 158.040 us; speedup vs baseline: 2.2012x; 1.4228x over previous
//
#include <hip/hip_runtime.h>
#include <stdint.h>

#define HIDDEN 1024
#define HEADS  16
#define DK     64
#define BATCH  2
#define SEQ    2048
#define MTOT   (BATCH*SEQ)
#define QSCALE 0.1803368801111204f  /* log2(e)/8 : folds softmax scale + exp2 conversion into Q */

typedef float  f32x4   __attribute__((ext_vector_type(4)));
typedef float  f32x16  __attribute__((ext_vector_type(16)));
typedef __bf16 bf16x8  __attribute__((ext_vector_type(8)));

__device__ __forceinline__ unsigned short f2bf(float f) {
    union { float f; uint32_t u; } x;
    x.f = f;
    uint32_t r = x.u + 0x7fffu + ((x.u >> 16) & 1u);
    return (unsigned short)(r >> 16);
}

__device__ __forceinline__ bf16x8 ld_bf8(const unsigned short* p) {
    return *reinterpret_cast<const bf16x8*>(p);
}

__device__ __forceinline__ void gload16(const void* g, void* l) {
    __builtin_amdgcn_global_load_lds(
        (const __attribute__((address_space(1))) void*)g,
        (__attribute__((address_space(3))) void*)l, 16, 0, 0);
}

__device__ __forceinline__ uint32_t pkbf(float a, float b) {
    union { __bf16 h[2]; uint32_t u; } pk;
    pk.h[0] = (__bf16)a; pk.h[1] = (__bf16)b;
    return pk.u;
}

// ---------------- fused fp32 -> bf16 convert for all 7 tensors ----------------
struct Cvt7 {
    const float* s[7];
    unsigned short* d[7];
    int n8[7];
};
__global__ __launch_bounds__(256) void cvt_all(Cvt7 a) {
    int id = blockIdx.y;
    int i = blockIdx.x * blockDim.x + threadIdx.x;
    if (i >= a.n8[id]) return;
    const float4* s = reinterpret_cast<const float4*>(a.s[id]) + (size_t)i * 2;
    float4 x = s[0], y = s[1];
    union { unsigned short us[8]; uint4 v; } o;
    o.us[0] = f2bf(x.x); o.us[1] = f2bf(x.y); o.us[2] = f2bf(x.z); o.us[3] = f2bf(x.w);
    o.us[4] = f2bf(y.x); o.us[5] = f2bf(y.y); o.us[6] = f2bf(y.z); o.us[7] = f2bf(y.w);
    reinterpret_cast<uint4*>(a.d[id])[i] = o.v;
}

// ---------------- GEMM body: C[M,N] = A[M,K]bf16 * W[N,K]^T bf16 + bias ----------------
__device__ __forceinline__ void gemm_body(const unsigned short* __restrict__ A,
                                          const unsigned short* __restrict__ W,
                                          const float* __restrict__ bias,
                                          void* __restrict__ out, int mode, float scale) {
    __shared__ __align__(16) unsigned short Alds[128 * 64];
    __shared__ __align__(16) unsigned short Blds[128 * 64];
    const int t    = threadIdx.x;
    const int lane = t & 63;
    const int wid  = t >> 6;
    const int wm   = (wid >> 1) * 64;
    const int wn   = (wid & 1) * 64;
    const int fr   = lane & 15;
    const int fg   = lane >> 4;
    const int bm   = blockIdx.y, bn = blockIdx.x;
    const int K    = HIDDEN;

    f32x4 acc[4][4];
#pragma unroll
    for (int i = 0; i < 4; i++)
#pragma unroll
        for (int j = 0; j < 4; j++) acc[i][j] = (f32x4){0.f, 0.f, 0.f, 0.f};

    const int seg_row = t >> 3;
    const int seg_col = (t & 7) * 8;

    for (int k0 = 0; k0 < K; k0 += 64) {
#pragma unroll
        for (int i = 0; i < 4; i++) {
            int row = i * 32 + seg_row;
            const unsigned short* ga = A + (size_t)(bm * 128 + row) * K + k0 + seg_col;
            const unsigned short* gb = W + (size_t)(bn * 128 + row) * K + k0 + seg_col;
            unsigned short* la = Alds + (size_t)(i * 256 + (t & ~63)) * 8;
            unsigned short* lb = Blds + (size_t)(i * 256 + (t & ~63)) * 8;
            gload16(ga, la);
            gload16(gb, lb);
        }
        __syncthreads();
#pragma unroll
        for (int kk = 0; kk < 2; kk++) {
            bf16x8 af[4], bf[4];
#pragma unroll
            for (int mt = 0; mt < 4; mt++)
                af[mt] = ld_bf8(&Alds[(wm + mt * 16 + fr) * 64 + kk * 32 + fg * 8]);
#pragma unroll
            for (int nt = 0; nt < 4; nt++)
                bf[nt] = ld_bf8(&Blds[(wn + nt * 16 + fr) * 64 + kk * 32 + fg * 8]);
#pragma unroll
            for (int mt = 0; mt < 4; mt++)
#pragma unroll
                for (int nt = 0; nt < 4; nt++)
                    acc[mt][nt] = __builtin_amdgcn_mfma_f32_16x16x32_bf16(
                        af[mt], bf[nt], acc[mt][nt], 0, 0, 0);
        }
        __syncthreads();
    }

    const int base_row = bm * 128 + wm + fg * 4;
    const int base_col = bn * 128 + wn + fr;
#pragma unroll
    for (int mt = 0; mt < 4; mt++) {
#pragma unroll
        for (int nt = 0; nt < 4; nt++) {
            int col = base_col + nt * 16;
            float bv = bias[col];
#pragma unroll
            for (int e = 0; e < 4; e++) {
                int row = base_row + mt * 16 + e;
                float val = (acc[mt][nt][e] + bv) * scale;
                if (mode == 2) {
                    ((float*)out)[(size_t)row * HIDDEN + col] = val;
                } else {
                    int b = row >> 11, s = row & (SEQ - 1);
                    int h = col >> 6, d = col & (DK - 1);
                    size_t idx;
                    if (mode == 0)
                        idx = ((size_t)(b * HEADS + h) * SEQ + s) * DK + d;
                    else
                        idx = ((size_t)(b * HEADS + h) * DK + d) * SEQ + s;
                    ((unsigned short*)out)[idx] = f2bf(val);
                }
            }
        }
    }
}

__global__ __launch_bounds__(256) void gemm_qkv(
    const unsigned short* __restrict__ qbf, const unsigned short* __restrict__ kbf,
    const unsigned short* __restrict__ vbf, const unsigned short* __restrict__ wq,
    const unsigned short* __restrict__ wk, const unsigned short* __restrict__ wv,
    const float* __restrict__ bq, const float* __restrict__ bk,
    const float* __restrict__ bv, unsigned short* __restrict__ qh,
    unsigned short* __restrict__ kh, unsigned short* __restrict__ vt) {
    int z = blockIdx.z;
    const unsigned short* A = (z == 0) ? qbf : (z == 1) ? kbf : vbf;
    const unsigned short* W = (z == 0) ? wq : (z == 1) ? wk : wv;
    const float* bias       = (z == 0) ? bq : (z == 1) ? bk : bv;
    unsigned short* out     = (z == 0) ? qh : (z == 1) ? kh : vt;
    gemm_body(A, W, bias, out, (z == 2) ? 1 : 0, (z == 0) ? QSCALE : 1.0f);
}

__global__ __launch_bounds__(256) void gemm_out(const unsigned short* __restrict__ ctx,
                                                const unsigned short* __restrict__ wo,
                                                const float* __restrict__ bo,
                                                float* __restrict__ out) {
    gemm_body(ctx, wo, bo, out, 2, 1.0f);
}

// ---------------- flash attention v4: LDS-staged K/V, 8 waves, double-buffered ----------------
// grid 512 (XCD-chunked: by=g>>4 0..31, bx=g&15). block 512 = 8 waves.
// wave w: qsub=w&3 (32 q rows of the 128-row block), split=w>>2 (keys [split*1024,+1024)).
// Per 64-key iter, K[64][64] and V^T[64][64] tiles for BOTH splits staged via
// global_load_lds (linear dest) with inverse-XOR-swizzled global source; reads
// apply the same XOR (rule #21). Double-buffered, 2-phase (T3 minimum).
__global__ __launch_bounds__(512, 4) void attn_kernel(const unsigned short* __restrict__ qh,
                                                      const unsigned short* __restrict__ kh,
                                                      const unsigned short* __restrict__ vt,
                                                      unsigned short* __restrict__ ctx) {
    const int t = threadIdx.x, lane = t & 63, w = t >> 6;
    const int lo = lane & 31, hi = lane >> 5;
    const int qsub = w & 3, split = w >> 2;
    const int id = blockIdx.x;
    const int g  = (id & 7) * 64 + (id >> 3);   // XCD-chunked: 4 heads per XCD
    const int by = g >> 4;                       // head-batch 0..31
    const int bx = g & 15;                       // 128-row q block 0..15
    const size_t hb = (size_t)by * (SEQ * DK);
    const int q0 = bx * 128 + qsub * 32;

    struct KV { unsigned short K[2][2][64 * 64]; unsigned short V[2][2][64 * 64]; };
    struct MG { float Lo[4][32][64]; float Lml[4][2][64]; };
    __shared__ union SMem { KV kv; MG mg; } sm;

    // ---- staging setup: 32 units of 8 rows x 128B; wave w owns units w*4..w*4+3 ----
    // unit u: u<16 -> K, else V; ssp=(u>>3)&1; r0=(u&7)*8.
    // lane covers (row = r0 + lane>>3, c = lane&7); source fetches column c ^ (row&7)
    // so that a linear LDS write yields the swizzled layout.
    const unsigned short* sp[4];
    unsigned short* dpK[4];
    int sstr[4];
#pragma unroll
    for (int i = 0; i < 4; ++i) {
        int u   = w * 4 + i;
        int isV = u >> 4;
        int ssp = (u >> 3) & 1;
        int r0  = (u & 7) * 8;
        int rl  = r0 + (lane >> 3);
        int cs  = ((lane & 7) ^ ((lane >> 3) & 7)) * 8;
        if (!isV) {
            sp[i]   = kh + hb + (size_t)(ssp * 1024 + rl) * DK + cs;
            sstr[i] = 64 * DK;
            dpK[i]  = &sm.kv.K[0][ssp][r0 * 64];
        } else {
            sp[i]   = vt + hb + (size_t)rl * SEQ + ssp * 1024 + cs;
            sstr[i] = 64;
            dpK[i]  = &sm.kv.V[0][ssp][r0 * 64];
        }
    }
    const int bufoff = 2 * 64 * 64;  // elements between buf0 and buf1 (same for K and V)

    // Q as B-fragments: col=q=lo, k=dk
    bf16x8 qf[4];
#pragma unroll
    for (int tl = 0; tl < 4; ++tl)
        qf[tl] = ld_bf8(&qh[hb + (size_t)(q0 + lo) * DK + tl * 16 + hi * 8]);

    f32x16 o0, o1;
#pragma unroll
    for (int e = 0; e < 16; ++e) { o0[e] = 0.f; o1[e] = 0.f; }
    float m = -3.0e38f, l = 0.f;

    // prologue: stage tile 0 into buf 0
#pragma unroll
    for (int i = 0; i < 4; ++i) { gload16(sp[i], dpK[i]); sp[i] += sstr[i]; }
    __syncthreads();

    const int xr = lo & 7;  // read-side XOR key (same for rows lo and 32+lo)

    for (int it = 0; it < 16; ++it) {
        const unsigned short* Kb = &sm.kv.K[it & 1][split][0];
        const unsigned short* Vb = &sm.kv.V[it & 1][split][0];
        // stage next tile into the other buffer
        if (it < 15) {
#pragma unroll
            for (int i = 0; i < 4; ++i) {
                unsigned short* d = dpK[i] + ((it & 1) ? 0 : bufoff);
                gload16(sp[i], d);
                sp[i] += sstr[i];
            }
        }
        // S^T[key, q] = K * Q^T for two 32-key tiles
        f32x16 sA, sB;
#pragma unroll
        for (int e = 0; e < 16; ++e) { sA[e] = 0.f; sB[e] = 0.f; }
        __builtin_amdgcn_s_setprio(1);
#pragma unroll
        for (int tl = 0; tl < 4; ++tl) {
            int c = 2 * tl + hi;
            bf16x8 kfA = ld_bf8(&Kb[lo * 64 + ((c ^ xr) * 8)]);
            bf16x8 kfB = ld_bf8(&Kb[(32 + lo) * 64 + ((c ^ xr) * 8)]);
            sA = __builtin_amdgcn_mfma_f32_32x32x16_bf16(kfA, qf[tl], sA, 0, 0, 0);
            sB = __builtin_amdgcn_mfma_f32_32x32x16_bf16(kfB, qf[tl], sB, 0, 0, 0);
        }
        __builtin_amdgcn_s_setprio(0);
        // online softmax over 64 keys
        float pm = sA[0];
#pragma unroll
        for (int e = 1; e < 16; ++e) pm = fmaxf(pm, sA[e]);
#pragma unroll
        for (int e = 0; e < 16; ++e) pm = fmaxf(pm, sB[e]);
        pm = fmaxf(pm, __shfl_xor(pm, 32));
        if (__any(pm > m + 8.f)) {  // defer-max (T13)
            float mn  = fmaxf(m, pm);
            float fac = __builtin_amdgcn_exp2f(m - mn);
            m = mn;
            l *= fac;
#pragma unroll
            for (int e = 0; e < 16; ++e) { o0[e] *= fac; o1[e] *= fac; }
        }
        float sum = 0.f;
#pragma unroll
        for (int e = 0; e < 16; ++e) {
            sA[e] = __builtin_amdgcn_exp2f(sA[e] - m);
            sB[e] = __builtin_amdgcn_exp2f(sB[e] - m);
            sum += sA[e] + sB[e];
        }
        sum += __shfl_xor(sum, 32);
        l += sum;
        // pack P to bf16 pairs; permlane32_swap yields both B-frag halves (T12)
        uint32_t pkA[8], pkB[8];
#pragma unroll
        for (int i = 0; i < 8; ++i) {
            pkA[i] = pkbf(sA[2 * i], sA[2 * i + 1]);
            pkB[i] = pkbf(sB[2 * i], sB[2 * i + 1]);
        }
        asm volatile("v_permlane32_swap_b32 %0, %1" : "+v"(pkA[0]), "+v"(pkA[2]));
        asm volatile("v_permlane32_swap_b32 %0, %1" : "+v"(pkA[1]), "+v"(pkA[3]));
        asm volatile("v_permlane32_swap_b32 %0, %1" : "+v"(pkA[4]), "+v"(pkA[6]));
        asm volatile("v_permlane32_swap_b32 %0, %1" : "+v"(pkA[5]), "+v"(pkA[7]));
        asm volatile("v_permlane32_swap_b32 %0, %1" : "+v"(pkB[0]), "+v"(pkB[2]));
        asm volatile("v_permlane32_swap_b32 %0, %1" : "+v"(pkB[1]), "+v"(pkB[3]));
        asm volatile("v_permlane32_swap_b32 %0, %1" : "+v"(pkB[4]), "+v"(pkB[6]));
        asm volatile("v_permlane32_swap_b32 %0, %1" : "+v"(pkB[5]), "+v"(pkB[7]));
        union { uint32_t u[4]; bf16x8 v; } f0, f1, f2, f3;
        f0.u[0] = pkA[0]; f0.u[1] = pkA[1]; f0.u[2] = pkA[2]; f0.u[3] = pkA[3];
        f1.u[0] = pkA[4]; f1.u[1] = pkA[5]; f1.u[2] = pkA[6]; f1.u[3] = pkA[7];
        f2.u[0] = pkB[0]; f2.u[1] = pkB[1]; f2.u[2] = pkB[2]; f2.u[3] = pkB[3];
        f3.u[0] = pkB[4]; f3.u[1] = pkB[5]; f3.u[2] = pkB[6]; f3.u[3] = pkB[7];
        // O^T[d, q] += V^T * P^T over 64 keys (V^T tile: row=dk, col=key)
        bf16x8 v00 = ld_bf8(&Vb[lo * 64 + (((0 + hi) ^ xr) * 8)]);
        bf16x8 v01 = ld_bf8(&Vb[lo * 64 + (((2 + hi) ^ xr) * 8)]);
        bf16x8 v02 = ld_bf8(&Vb[lo * 64 + (((4 + hi) ^ xr) * 8)]);
        bf16x8 v03 = ld_bf8(&Vb[lo * 64 + (((6 + hi) ^ xr) * 8)]);
        bf16x8 v10 = ld_bf8(&Vb[(32 + lo) * 64 + (((0 + hi) ^ xr) * 8)]);
        bf16x8 v11 = ld_bf8(&Vb[(32 + lo) * 64 + (((2 + hi) ^ xr) * 8)]);
        bf16x8 v12 = ld_bf8(&Vb[(32 + lo) * 64 + (((4 + hi) ^ xr) * 8)]);
        bf16x8 v13 = ld_bf8(&Vb[(32 + lo) * 64 + (((6 + hi) ^ xr) * 8)]);
        __builtin_amdgcn_s_setprio(1);
        o0 = __builtin_amdgcn_mfma_f32_32x32x16_bf16(v00, f0.v, o0, 0, 0, 0);
        o0 = __builtin_amdgcn_mfma_f32_32x32x16_bf16(v01, f1.v, o0, 0, 0, 0);
        o0 = __builtin_amdgcn_mfma_f32_32x32x16_bf16(v02, f2.v, o0, 0, 0, 0);
        o0 = __builtin_amdgcn_mfma_f32_32x32x16_bf16(v03, f3.v, o0, 0, 0, 0);
        o1 = __builtin_amdgcn_mfma_f32_32x32x16_bf16(v10, f0.v, o1, 0, 0, 0);
        o1 = __builtin_amdgcn_mfma_f32_32x32x16_bf16(v11, f1.v, o1, 0, 0, 0);
        o1 = __builtin_amdgcn_mfma_f32_32x32x16_bf16(v12, f2.v, o1, 0, 0, 0);
        o1 = __builtin_amdgcn_mfma_f32_32x32x16_bf16(v13, f3.v, o1, 0, 0, 0);
        __builtin_amdgcn_s_setprio(0);
        __syncthreads();  // drains vmcnt (next tile staged) + lgkm; flips buffers
    }

    // split-1 waves publish partials into the (now dead) K/V LDS space
    if (split == 1) {
#pragma unroll
        for (int e = 0; e < 16; ++e) {
            sm.mg.Lo[qsub][e][lane]      = o0[e];
            sm.mg.Lo[qsub][16 + e][lane] = o1[e];
        }
        sm.mg.Lml[qsub][0][lane] = m;
        sm.mg.Lml[qsub][1][lane] = l;
    }
    __syncthreads();
    if (split == 0) {
        float m2 = sm.mg.Lml[qsub][0][lane];
        float l2 = sm.mg.Lml[qsub][1][lane];
        float M  = fmaxf(m, m2);
        float a0 = __builtin_amdgcn_exp2f(m - M);
        float a1 = __builtin_amdgcn_exp2f(m2 - M);
        float rl = __builtin_amdgcn_rcpf(a0 * l + a1 * l2);
        const int b = by >> 4, hd = by & 15;
        unsigned short* orow = ctx + ((size_t)(b * SEQ + q0 + lo)) * HIDDEN + hd * 64;
#pragma unroll
        for (int dt = 0; dt < 2; ++dt) {
#pragma unroll
            for (int gq = 0; gq < 4; ++gq) {
                union { unsigned short us[4]; uint2 v; } pk;
#pragma unroll
                for (int c = 0; c < 4; ++c) {
                    int e = gq * 4 + c;
                    float own = dt ? o1[e] : o0[e];
                    float oth = sm.mg.Lo[qsub][dt * 16 + e][lane];
                    pk.us[c] = f2bf((own * a0 + oth * a1) * rl);
                }
                *reinterpret_cast<uint2*>(orow + dt * 32 + gq * 8 + hi * 4) = pk.v;
            }
        }
    }
}

// ---------------- launch ----------------
extern "C" void kernel_launch(void* const* d_in, const int* in_sizes, int n_in,
                              void* d_out, int out_size, void* d_ws, size_t ws_size,
                              hipStream_t stream) {
    const float* q  = (const float*)d_in[0];
    const float* k  = (const float*)d_in[1];
    const float* v  = (const float*)d_in[2];
    const float* Wq = (const float*)d_in[3];
    const float* bq = (const float*)d_in[4];
    const float* Wk = (const float*)d_in[5];
    const float* bk = (const float*)d_in[6];
    const float* Wv = (const float*)d_in[7];
    const float* bv = (const float*)d_in[8];
    const float* Wo = (const float*)d_in[9];
    const float* bo = (const float*)d_in[10];

    unsigned short* qbf = (unsigned short*)d_ws;
    unsigned short* kbf = qbf + (size_t)MTOT * HIDDEN;
    unsigned short* vbf = kbf + (size_t)MTOT * HIDDEN;
    unsigned short* wqb = vbf + (size_t)MTOT * HIDDEN;
    unsigned short* wkb = wqb + (size_t)HIDDEN * HIDDEN;
    unsigned short* wvb = wkb + (size_t)HIDDEN * HIDDEN;
    unsigned short* wob = wvb + (size_t)HIDDEN * HIDDEN;
    unsigned short* qh  = wob + (size_t)HIDDEN * HIDDEN;
    unsigned short* kh  = qh + (size_t)MTOT * HIDDEN;
    unsigned short* vt  = kh + (size_t)MTOT * HIDDEN;
    unsigned short* ctx = vt + (size_t)MTOT * HIDDEN;

    const int nAct8 = MTOT * HIDDEN / 8;    // 524288
    const int nW8   = HIDDEN * HIDDEN / 8;  // 131072

    Cvt7 ca;
    ca.s[0] = q;  ca.d[0] = qbf; ca.n8[0] = nAct8;
    ca.s[1] = k;  ca.d[1] = kbf; ca.n8[1] = nAct8;
    ca.s[2] = v;  ca.d[2] = vbf; ca.n8[2] = nAct8;
    ca.s[3] = Wq; ca.d[3] = wqb; ca.n8[3] = nW8;
    ca.s[4] = Wk; ca.d[4] = wkb; ca.n8[4] = nW8;
    ca.s[5] = Wv; ca.d[5] = wvb; ca.n8[5] = nW8;
    ca.s[6] = Wo; ca.d[6] = wob; ca.n8[6] = nW8;
    cvt_all<<<dim3(nAct8 / 256, 7), dim3(256), 0, stream>>>(ca);

    gemm_qkv<<<dim3(HIDDEN / 128, MTOT / 128, 3), dim3(256), 0, stream>>>(
        qbf, kbf, vbf, wqb, wkb, wvb, bq, bk, bv, qh, kh, vt);

    attn_kernel<<<dim3(512), dim3(512), 0, stream>>>(qh, kh, vt, ctx);

    gemm_out<<<dim3(HIDDEN / 128, MTOT / 128), dim3(256), 0, stream>>>(
        ctx, wob, bo, (float*)d_out);
}

// Round 6
// 147.758 us; speedup vs baseline: 2.3544x; 1.0696x over previous
//
#include <hip/hip_runtime.h>
#include <stdint.h>

#define HIDDEN 1024
#define HEADS  16
#define DK     64
#define BATCH  2
#define SEQ    2048
#define MTOT   (BATCH*SEQ)
#define QSCALE 0.1803368801111204f  /* log2(e)/8 : folds softmax scale + exp2 conversion into Q */

typedef float  f32x4   __attribute__((ext_vector_type(4)));
typedef float  f32x16  __attribute__((ext_vector_type(16)));
typedef __bf16 bf16x8  __attribute__((ext_vector_type(8)));

__device__ __forceinline__ unsigned short f2bf(float f) {
    union { float f; uint32_t u; } x;
    x.f = f;
    uint32_t r = x.u + 0x7fffu + ((x.u >> 16) & 1u);
    return (unsigned short)(r >> 16);
}

__device__ __forceinline__ bf16x8 ld_bf8(const unsigned short* p) {
    return *reinterpret_cast<const bf16x8*>(p);
}

__device__ __forceinline__ void gload16(const void* g, void* l) {
    __builtin_amdgcn_global_load_lds(
        (const __attribute__((address_space(1))) void*)g,
        (__attribute__((address_space(3))) void*)l, 16, 0, 0);
}

__device__ __forceinline__ uint32_t pkbf(float a, float b) {
    union { __bf16 h[2]; uint32_t u; } pk;
    pk.h[0] = (__bf16)a; pk.h[1] = (__bf16)b;
    return pk.u;
}

// ---------------- fused fp32 -> bf16 convert for all 7 tensors ----------------
struct Cvt7 {
    const float* s[7];
    unsigned short* d[7];
    int n8[7];
};
__global__ __launch_bounds__(256) void cvt_all(Cvt7 a) {
    int id = blockIdx.y;
    int i = blockIdx.x * blockDim.x + threadIdx.x;
    if (i >= a.n8[id]) return;
    const float4* s = reinterpret_cast<const float4*>(a.s[id]) + (size_t)i * 2;
    float4 x = s[0], y = s[1];
    union { unsigned short us[8]; uint4 v; } o;
    o.us[0] = f2bf(x.x); o.us[1] = f2bf(x.y); o.us[2] = f2bf(x.z); o.us[3] = f2bf(x.w);
    o.us[4] = f2bf(y.x); o.us[5] = f2bf(y.y); o.us[6] = f2bf(y.z); o.us[7] = f2bf(y.w);
    reinterpret_cast<uint4*>(a.d[id])[i] = o.v;
}

// ---------------- GEMM body v3: round-4 semantics + prefetch dbuf + XOR swizzle ----------------
// C[M,N] = A[M,K] * W[N,K]^T + bias, bf16 in, 128x128 tile, BK=64.
// mode 0: bf16 out, [B,H,S,DK] scatter (rows=tokens, cols=features)  (q,k proj)
// mode 1: bf16 out, [B,H,DK,S] scatter (rows=tokens, cols=features)  (v proj -> V^T)
// mode 2: f32  out, row-major [M,N]                                  (final proj)
// LDS swizzle (rule #21 both-sides, same key math as the proven attn staging):
// linear gload_lds dest; source fetches granule (t&7)^(row&7); ds_read XORs same key.
__device__ __forceinline__ void gemm_body(const unsigned short* __restrict__ A,
                                          const unsigned short* __restrict__ W,
                                          const float* __restrict__ bias,
                                          void* __restrict__ out, int mode, float scale) {
    __shared__ __align__(16) unsigned short Alds[2][128 * 64];
    __shared__ __align__(16) unsigned short Blds[2][128 * 64];
    const int t    = threadIdx.x;
    const int lane = t & 63;
    const int wid  = t >> 6;
    const int wm   = (wid >> 1) * 64;
    const int wn   = (wid & 1) * 64;
    const int fr   = lane & 15;
    const int fg   = lane >> 4;
    const int bm   = blockIdx.y, bn = blockIdx.x;
    const int K    = HIDDEN;

    f32x4 acc[4][4];
#pragma unroll
    for (int i = 0; i < 4; i++)
#pragma unroll
        for (int j = 0; j < 4; j++) acc[i][j] = (f32x4){0.f, 0.f, 0.f, 0.f};

    const int seg_row = t >> 3;                              // 0..31 per load
    const int seg_col = ((t & 7) ^ (seg_row & 7)) * 8;       // inverse-swizzled source granule
    const int ldst    = (t & ~63) * 8;                       // per-wave linear LDS base (shorts)

    const unsigned short* ga = A + (size_t)(bm * 128 + seg_row) * K + seg_col;
    const unsigned short* gb = W + (size_t)(bn * 128 + seg_row) * K + seg_col;

    auto stage = [&](int k0, int buf) {
#pragma unroll
        for (int i = 0; i < 4; i++) {
            gload16(ga + (size_t)(i * 32) * K + k0, &Alds[buf][i * 2048 + ldst]);
            gload16(gb + (size_t)(i * 32) * K + k0, &Blds[buf][i * 2048 + ldst]);
        }
    };

    stage(0, 0);
    __syncthreads();

    for (int ks = 0; ks < K / 64; ++ks) {
        const int cur = ks & 1;
        if (ks < K / 64 - 1) stage((ks + 1) * 64, cur ^ 1);   // prefetch in flight during compute
#pragma unroll
        for (int kk = 0; kk < 2; kk++) {
            bf16x8 af[4], bf[4];
#pragma unroll
            for (int mt = 0; mt < 4; mt++)
                af[mt] = ld_bf8(&Alds[cur][(wm + mt * 16 + fr) * 64 +
                                           (((kk * 4 + fg) ^ (fr & 7)) * 8)]);
#pragma unroll
            for (int nt = 0; nt < 4; nt++)
                bf[nt] = ld_bf8(&Blds[cur][(wn + nt * 16 + fr) * 64 +
                                           (((kk * 4 + fg) ^ (fr & 7)) * 8)]);
#pragma unroll
            for (int mt = 0; mt < 4; mt++)
#pragma unroll
                for (int nt = 0; nt < 4; nt++)
                    acc[mt][nt] = __builtin_amdgcn_mfma_f32_16x16x32_bf16(
                        af[mt], bf[nt], acc[mt][nt], 0, 0, 0);
        }
        __syncthreads();   // drains prefetch vmcnt + guards buffer reuse (one barrier/K-step)
    }

    // ---- round-4 epilogue verbatim ----
    const int base_row = bm * 128 + wm + fg * 4;
    const int base_col = bn * 128 + wn + fr;
#pragma unroll
    for (int mt = 0; mt < 4; mt++) {
#pragma unroll
        for (int nt = 0; nt < 4; nt++) {
            int col = base_col + nt * 16;
            float bv = bias[col];
#pragma unroll
            for (int e = 0; e < 4; e++) {
                int row = base_row + mt * 16 + e;
                float val = (acc[mt][nt][e] + bv) * scale;
                if (mode == 2) {
                    ((float*)out)[(size_t)row * HIDDEN + col] = val;
                } else {
                    int b = row >> 11, s = row & (SEQ - 1);
                    int h = col >> 6, d = col & (DK - 1);
                    size_t idx;
                    if (mode == 0)
                        idx = ((size_t)(b * HEADS + h) * SEQ + s) * DK + d;
                    else
                        idx = ((size_t)(b * HEADS + h) * DK + d) * SEQ + s;
                    ((unsigned short*)out)[idx] = f2bf(val);
                }
            }
        }
    }
}

__global__ __launch_bounds__(256) void gemm_qkv(
    const unsigned short* __restrict__ qbf, const unsigned short* __restrict__ kbf,
    const unsigned short* __restrict__ vbf, const unsigned short* __restrict__ wq,
    const unsigned short* __restrict__ wk, const unsigned short* __restrict__ wv,
    const float* __restrict__ bq, const float* __restrict__ bk,
    const float* __restrict__ bv, unsigned short* __restrict__ qh,
    unsigned short* __restrict__ kh, unsigned short* __restrict__ vt) {
    int z = blockIdx.z;
    const unsigned short* A = (z == 0) ? qbf : (z == 1) ? kbf : vbf;
    const unsigned short* W = (z == 0) ? wq : (z == 1) ? wk : wv;
    const float* bias       = (z == 0) ? bq : (z == 1) ? bk : bv;
    unsigned short* out     = (z == 0) ? qh : (z == 1) ? kh : vt;
    gemm_body(A, W, bias, out, (z == 2) ? 1 : 0, (z == 0) ? QSCALE : 1.0f);
}

__global__ __launch_bounds__(256) void gemm_out(const unsigned short* __restrict__ ctx,
                                                const unsigned short* __restrict__ wo,
                                                const float* __restrict__ bo,
                                                float* __restrict__ out) {
    gemm_body(ctx, wo, bo, out, 2, 1.0f);
}

// ---------------- flash attention v4: LDS-staged K/V, 8 waves, double-buffered ----------------
// (unchanged from round 4, which passed)
__global__ __launch_bounds__(512, 4) void attn_kernel(const unsigned short* __restrict__ qh,
                                                      const unsigned short* __restrict__ kh,
                                                      const unsigned short* __restrict__ vt,
                                                      unsigned short* __restrict__ ctx) {
    const int t = threadIdx.x, lane = t & 63, w = t >> 6;
    const int lo = lane & 31, hi = lane >> 5;
    const int qsub = w & 3, split = w >> 2;
    const int id = blockIdx.x;
    const int g  = (id & 7) * 64 + (id >> 3);   // XCD-chunked: 4 heads per XCD
    const int by = g >> 4;
    const int bx = g & 15;
    const size_t hb = (size_t)by * (SEQ * DK);
    const int q0 = bx * 128 + qsub * 32;

    struct KV { unsigned short K[2][2][64 * 64]; unsigned short V[2][2][64 * 64]; };
    struct MG { float Lo[4][32][64]; float Lml[4][2][64]; };
    __shared__ union SMem { KV kv; MG mg; } sm;

    const unsigned short* sp[4];
    unsigned short* dpK[4];
    int sstr[4];
#pragma unroll
    for (int i = 0; i < 4; ++i) {
        int u   = w * 4 + i;
        int isV = u >> 4;
        int ssp = (u >> 3) & 1;
        int r0  = (u & 7) * 8;
        int rl  = r0 + (lane >> 3);
        int cs  = ((lane & 7) ^ ((lane >> 3) & 7)) * 8;
        if (!isV) {
            sp[i]   = kh + hb + (size_t)(ssp * 1024 + rl) * DK + cs;
            sstr[i] = 64 * DK;
            dpK[i]  = &sm.kv.K[0][ssp][r0 * 64];
        } else {
            sp[i]   = vt + hb + (size_t)rl * SEQ + ssp * 1024 + cs;
            sstr[i] = 64;
            dpK[i]  = &sm.kv.V[0][ssp][r0 * 64];
        }
    }
    const int bufoff = 2 * 64 * 64;

    bf16x8 qf[4];
#pragma unroll
    for (int tl = 0; tl < 4; ++tl)
        qf[tl] = ld_bf8(&qh[hb + (size_t)(q0 + lo) * DK + tl * 16 + hi * 8]);

    f32x16 o0, o1;
#pragma unroll
    for (int e = 0; e < 16; ++e) { o0[e] = 0.f; o1[e] = 0.f; }
    float m = -3.0e38f, l = 0.f;

#pragma unroll
    for (int i = 0; i < 4; ++i) { gload16(sp[i], dpK[i]); sp[i] += sstr[i]; }
    __syncthreads();

    const int xr = lo & 7;

    for (int it = 0; it < 16; ++it) {
        const unsigned short* Kb = &sm.kv.K[it & 1][split][0];
        const unsigned short* Vb = &sm.kv.V[it & 1][split][0];
        if (it < 15) {
#pragma unroll
            for (int i = 0; i < 4; ++i) {
                unsigned short* d = dpK[i] + ((it & 1) ? 0 : bufoff);
                gload16(sp[i], d);
                sp[i] += sstr[i];
            }
        }
        f32x16 sA, sB;
#pragma unroll
        for (int e = 0; e < 16; ++e) { sA[e] = 0.f; sB[e] = 0.f; }
        __builtin_amdgcn_s_setprio(1);
#pragma unroll
        for (int tl = 0; tl < 4; ++tl) {
            int c = 2 * tl + hi;
            bf16x8 kfA = ld_bf8(&Kb[lo * 64 + ((c ^ xr) * 8)]);
            bf16x8 kfB = ld_bf8(&Kb[(32 + lo) * 64 + ((c ^ xr) * 8)]);
            sA = __builtin_amdgcn_mfma_f32_32x32x16_bf16(kfA, qf[tl], sA, 0, 0, 0);
            sB = __builtin_amdgcn_mfma_f32_32x32x16_bf16(kfB, qf[tl], sB, 0, 0, 0);
        }
        __builtin_amdgcn_s_setprio(0);
        float pm = sA[0];
#pragma unroll
        for (int e = 1; e < 16; ++e) pm = fmaxf(pm, sA[e]);
#pragma unroll
        for (int e = 0; e < 16; ++e) pm = fmaxf(pm, sB[e]);
        pm = fmaxf(pm, __shfl_xor(pm, 32));
        if (__any(pm > m + 8.f)) {
            float mn  = fmaxf(m, pm);
            float fac = __builtin_amdgcn_exp2f(m - mn);
            m = mn;
            l *= fac;
#pragma unroll
            for (int e = 0; e < 16; ++e) { o0[e] *= fac; o1[e] *= fac; }
        }
        float sum = 0.f;
#pragma unroll
        for (int e = 0; e < 16; ++e) {
            sA[e] = __builtin_amdgcn_exp2f(sA[e] - m);
            sB[e] = __builtin_amdgcn_exp2f(sB[e] - m);
            sum += sA[e] + sB[e];
        }
        sum += __shfl_xor(sum, 32);
        l += sum;
        uint32_t pkA[8], pkB[8];
#pragma unroll
        for (int i = 0; i < 8; ++i) {
            pkA[i] = pkbf(sA[2 * i], sA[2 * i + 1]);
            pkB[i] = pkbf(sB[2 * i], sB[2 * i + 1]);
        }
        asm volatile("v_permlane32_swap_b32 %0, %1" : "+v"(pkA[0]), "+v"(pkA[2]));
        asm volatile("v_permlane32_swap_b32 %0, %1" : "+v"(pkA[1]), "+v"(pkA[3]));
        asm volatile("v_permlane32_swap_b32 %0, %1" : "+v"(pkA[4]), "+v"(pkA[6]));
        asm volatile("v_permlane32_swap_b32 %0, %1" : "+v"(pkA[5]), "+v"(pkA[7]));
        asm volatile("v_permlane32_swap_b32 %0, %1" : "+v"(pkB[0]), "+v"(pkB[2]));
        asm volatile("v_permlane32_swap_b32 %0, %1" : "+v"(pkB[1]), "+v"(pkB[3]));
        asm volatile("v_permlane32_swap_b32 %0, %1" : "+v"(pkB[4]), "+v"(pkB[6]));
        asm volatile("v_permlane32_swap_b32 %0, %1" : "+v"(pkB[5]), "+v"(pkB[7]));
        union { uint32_t u[4]; bf16x8 v; } f0, f1, f2, f3;
        f0.u[0] = pkA[0]; f0.u[1] = pkA[1]; f0.u[2] = pkA[2]; f0.u[3] = pkA[3];
        f1.u[0] = pkA[4]; f1.u[1] = pkA[5]; f1.u[2] = pkA[6]; f1.u[3] = pkA[7];
        f2.u[0] = pkB[0]; f2.u[1] = pkB[1]; f2.u[2] = pkB[2]; f2.u[3] = pkB[3];
        f3.u[0] = pkB[4]; f3.u[1] = pkB[5]; f3.u[2] = pkB[6]; f3.u[3] = pkB[7];
        bf16x8 v00 = ld_bf8(&Vb[lo * 64 + (((0 + hi) ^ xr) * 8)]);
        bf16x8 v01 = ld_bf8(&Vb[lo * 64 + (((2 + hi) ^ xr) * 8)]);
        bf16x8 v02 = ld_bf8(&Vb[lo * 64 + (((4 + hi) ^ xr) * 8)]);
        bf16x8 v03 = ld_bf8(&Vb[lo * 64 + (((6 + hi) ^ xr) * 8)]);
        bf16x8 v10 = ld_bf8(&Vb[(32 + lo) * 64 + (((0 + hi) ^ xr) * 8)]);
        bf16x8 v11 = ld_bf8(&Vb[(32 + lo) * 64 + (((2 + hi) ^ xr) * 8)]);
        bf16x8 v12 = ld_bf8(&Vb[(32 + lo) * 64 + (((4 + hi) ^ xr) * 8)]);
        bf16x8 v13 = ld_bf8(&Vb[(32 + lo) * 64 + (((6 + hi) ^ xr) * 8)]);
        __builtin_amdgcn_s_setprio(1);
        o0 = __builtin_amdgcn_mfma_f32_32x32x16_bf16(v00, f0.v, o0, 0, 0, 0);
        o0 = __builtin_amdgcn_mfma_f32_32x32x16_bf16(v01, f1.v, o0, 0, 0, 0);
        o0 = __builtin_amdgcn_mfma_f32_32x32x16_bf16(v02, f2.v, o0, 0, 0, 0);
        o0 = __builtin_amdgcn_mfma_f32_32x32x16_bf16(v03, f3.v, o0, 0, 0, 0);
        o1 = __builtin_amdgcn_mfma_f32_32x32x16_bf16(v10, f0.v, o1, 0, 0, 0);
        o1 = __builtin_amdgcn_mfma_f32_32x32x16_bf16(v11, f1.v, o1, 0, 0, 0);
        o1 = __builtin_amdgcn_mfma_f32_32x32x16_bf16(v12, f2.v, o1, 0, 0, 0);
        o1 = __builtin_amdgcn_mfma_f32_32x32x16_bf16(v13, f3.v, o1, 0, 0, 0);
        __builtin_amdgcn_s_setprio(0);
        __syncthreads();
    }

    if (split == 1) {
#pragma unroll
        for (int e = 0; e < 16; ++e) {
            sm.mg.Lo[qsub][e][lane]      = o0[e];
            sm.mg.Lo[qsub][16 + e][lane] = o1[e];
        }
        sm.mg.Lml[qsub][0][lane] = m;
        sm.mg.Lml[qsub][1][lane] = l;
    }
    __syncthreads();
    if (split == 0) {
        float m2 = sm.mg.Lml[qsub][0][lane];
        float l2 = sm.mg.Lml[qsub][1][lane];
        float M  = fmaxf(m, m2);
        float a0 = __builtin_amdgcn_exp2f(m - M);
        float a1 = __builtin_amdgcn_exp2f(m2 - M);
        float rl = __builtin_amdgcn_rcpf(a0 * l + a1 * l2);
        const int b = by >> 4, hd = by & 15;
        unsigned short* orow = ctx + ((size_t)(b * SEQ + q0 + lo)) * HIDDEN + hd * 64;
#pragma unroll
        for (int dt = 0; dt < 2; ++dt) {
#pragma unroll
            for (int gq = 0; gq < 4; ++gq) {
                union { unsigned short us[4]; uint2 v; } pk;
#pragma unroll
                for (int c = 0; c < 4; ++c) {
                    int e = gq * 4 + c;
                    float own = dt ? o1[e] : o0[e];
                    float oth = sm.mg.Lo[qsub][dt * 16 + e][lane];
                    pk.us[c] = f2bf((own * a0 + oth * a1) * rl);
                }
                *reinterpret_cast<uint2*>(orow + dt * 32 + gq * 8 + hi * 4) = pk.v;
            }
        }
    }
}

// ---------------- launch ----------------
extern "C" void kernel_launch(void* const* d_in, const int* in_sizes, int n_in,
                              void* d_out, int out_size, void* d_ws, size_t ws_size,
                              hipStream_t stream) {
    const float* q  = (const float*)d_in[0];
    const float* k  = (const float*)d_in[1];
    const float* v  = (const float*)d_in[2];
    const float* Wq = (const float*)d_in[3];
    const float* bq = (const float*)d_in[4];
    const float* Wk = (const float*)d_in[5];
    const float* bk = (const float*)d_in[6];
    const float* Wv = (const float*)d_in[7];
    const float* bv = (const float*)d_in[8];
    const float* Wo = (const float*)d_in[9];
    const float* bo = (const float*)d_in[10];

    unsigned short* qbf = (unsigned short*)d_ws;
    unsigned short* kbf = qbf + (size_t)MTOT * HIDDEN;
    unsigned short* vbf = kbf + (size_t)MTOT * HIDDEN;
    unsigned short* wqb = vbf + (size_t)MTOT * HIDDEN;
    unsigned short* wkb = wqb + (size_t)HIDDEN * HIDDEN;
    unsigned short* wvb = wkb + (size_t)HIDDEN * HIDDEN;
    unsigned short* wob = wvb + (size_t)HIDDEN * HIDDEN;
    unsigned short* qh  = wob + (size_t)HIDDEN * HIDDEN;
    unsigned short* kh  = qh + (size_t)MTOT * HIDDEN;
    unsigned short* vt  = kh + (size_t)MTOT * HIDDEN;
    unsigned short* ctx = vt + (size_t)MTOT * HIDDEN;

    const int nAct8 = MTOT * HIDDEN / 8;    // 524288
    const int nW8   = HIDDEN * HIDDEN / 8;  // 131072

    Cvt7 ca;
    ca.s[0] = q;  ca.d[0] = qbf; ca.n8[0] = nAct8;
    ca.s[1] = k;  ca.d[1] = kbf; ca.n8[1] = nAct8;
    ca.s[2] = v;  ca.d[2] = vbf; ca.n8[2] = nAct8;
    ca.s[3] = Wq; ca.d[3] = wqb; ca.n8[3] = nW8;
    ca.s[4] = Wk; ca.d[4] = wkb; ca.n8[4] = nW8;
    ca.s[5] = Wv; ca.d[5] = wvb; ca.n8[5] = nW8;
    ca.s[6] = Wo; ca.d[6] = wob; ca.n8[6] = nW8;
    cvt_all<<<dim3(nAct8 / 256, 7), dim3(256), 0, stream>>>(ca);

    gemm_qkv<<<dim3(HIDDEN / 128, MTOT / 128, 3), dim3(256), 0, stream>>>(
        qbf, kbf, vbf, wqb, wkb, wvb, bq, bk, bv, qh, kh, vt);

    attn_kernel<<<dim3(512), dim3(512), 0, stream>>>(qh, kh, vt, ctx);

    gemm_out<<<dim3(HIDDEN / 128, MTOT / 128), dim3(256), 0, stream>>>(
        ctx, wob, bo, (float*)d_out);
}

// Round 7
// 147.157 us; speedup vs baseline: 2.3640x; 1.0041x over previous
//
#include <hip/hip_runtime.h>
#include <stdint.h>

#define HIDDEN 1024
#define HEADS  16
#define DK     64
#define BATCH  2
#define SEQ    2048
#define MTOT   (BATCH*SEQ)
#define QSCALE 0.1803368801111204f  /* log2(e)/8 : folds softmax scale + exp2 conversion into Q */

typedef float  f32x4   __attribute__((ext_vector_type(4)));
typedef float  f32x16  __attribute__((ext_vector_type(16)));
typedef __bf16 bf16x8  __attribute__((ext_vector_type(8)));

__device__ __forceinline__ unsigned short f2bf(float f) {
    union { float f; uint32_t u; } x;
    x.f = f;
    uint32_t r = x.u + 0x7fffu + ((x.u >> 16) & 1u);
    return (unsigned short)(r >> 16);
}

__device__ __forceinline__ bf16x8 ld_bf8(const unsigned short* p) {
    return *reinterpret_cast<const bf16x8*>(p);
}

__device__ __forceinline__ void gload16(const void* g, void* l) {
    __builtin_amdgcn_global_load_lds(
        (const __attribute__((address_space(1))) void*)g,
        (__attribute__((address_space(3))) void*)l, 16, 0, 0);
}

__device__ __forceinline__ uint32_t pkbf(float a, float b) {
    union { __bf16 h[2]; uint32_t u; } pk;
    pk.h[0] = (__bf16)a; pk.h[1] = (__bf16)b;
    return pk.u;
}

__device__ __forceinline__ float tmax16(const f32x16& v) {
    float a = fmaxf(fmaxf(v[0], v[1]), fmaxf(v[2], v[3]));
    float b = fmaxf(fmaxf(v[4], v[5]), fmaxf(v[6], v[7]));
    float c = fmaxf(fmaxf(v[8], v[9]), fmaxf(v[10], v[11]));
    float d = fmaxf(fmaxf(v[12], v[13]), fmaxf(v[14], v[15]));
    return fmaxf(fmaxf(a, b), fmaxf(c, d));
}

__device__ __forceinline__ float tsum16(const f32x16& v) {
    float a = (v[0] + v[1]) + (v[2] + v[3]);
    float b = (v[4] + v[5]) + (v[6] + v[7]);
    float c = (v[8] + v[9]) + (v[10] + v[11]);
    float d = (v[12] + v[13]) + (v[14] + v[15]);
    return (a + b) + (c + d);
}

// ---------------- fused fp32 -> bf16 convert for all 7 tensors ----------------
struct Cvt7 {
    const float* s[7];
    unsigned short* d[7];
    int n8[7];
};
__global__ __launch_bounds__(256) void cvt_all(Cvt7 a) {
    int id = blockIdx.y;
    int i = blockIdx.x * blockDim.x + threadIdx.x;
    if (i >= a.n8[id]) return;
    const float4* s = reinterpret_cast<const float4*>(a.s[id]) + (size_t)i * 2;
    float4 x = s[0], y = s[1];
    union { unsigned short us[8]; uint4 v; } o;
    o.us[0] = f2bf(x.x); o.us[1] = f2bf(x.y); o.us[2] = f2bf(x.z); o.us[3] = f2bf(x.w);
    o.us[4] = f2bf(y.x); o.us[5] = f2bf(y.y); o.us[6] = f2bf(y.z); o.us[7] = f2bf(y.w);
    reinterpret_cast<uint4*>(a.d[id])[i] = o.v;
}

// ---------------- GEMM body v3 (unchanged from round 6, passing) ----------------
__device__ __forceinline__ void gemm_body(const unsigned short* __restrict__ A,
                                          const unsigned short* __restrict__ W,
                                          const float* __restrict__ bias,
                                          void* __restrict__ out, int mode, float scale) {
    __shared__ __align__(16) unsigned short Alds[2][128 * 64];
    __shared__ __align__(16) unsigned short Blds[2][128 * 64];
    const int t    = threadIdx.x;
    const int lane = t & 63;
    const int wid  = t >> 6;
    const int wm   = (wid >> 1) * 64;
    const int wn   = (wid & 1) * 64;
    const int fr   = lane & 15;
    const int fg   = lane >> 4;
    const int bm   = blockIdx.y, bn = blockIdx.x;
    const int K    = HIDDEN;

    f32x4 acc[4][4];
#pragma unroll
    for (int i = 0; i < 4; i++)
#pragma unroll
        for (int j = 0; j < 4; j++) acc[i][j] = (f32x4){0.f, 0.f, 0.f, 0.f};

    const int seg_row = t >> 3;
    const int seg_col = ((t & 7) ^ (seg_row & 7)) * 8;
    const int ldst    = (t & ~63) * 8;

    const unsigned short* ga = A + (size_t)(bm * 128 + seg_row) * K + seg_col;
    const unsigned short* gb = W + (size_t)(bn * 128 + seg_row) * K + seg_col;

    auto stage = [&](int k0, int buf) {
#pragma unroll
        for (int i = 0; i < 4; i++) {
            gload16(ga + (size_t)(i * 32) * K + k0, &Alds[buf][i * 2048 + ldst]);
            gload16(gb + (size_t)(i * 32) * K + k0, &Blds[buf][i * 2048 + ldst]);
        }
    };

    stage(0, 0);
    __syncthreads();

    for (int ks = 0; ks < K / 64; ++ks) {
        const int cur = ks & 1;
        if (ks < K / 64 - 1) stage((ks + 1) * 64, cur ^ 1);
#pragma unroll
        for (int kk = 0; kk < 2; kk++) {
            bf16x8 af[4], bf[4];
#pragma unroll
            for (int mt = 0; mt < 4; mt++)
                af[mt] = ld_bf8(&Alds[cur][(wm + mt * 16 + fr) * 64 +
                                           (((kk * 4 + fg) ^ (fr & 7)) * 8)]);
#pragma unroll
            for (int nt = 0; nt < 4; nt++)
                bf[nt] = ld_bf8(&Blds[cur][(wn + nt * 16 + fr) * 64 +
                                           (((kk * 4 + fg) ^ (fr & 7)) * 8)]);
#pragma unroll
            for (int mt = 0; mt < 4; mt++)
#pragma unroll
                for (int nt = 0; nt < 4; nt++)
                    acc[mt][nt] = __builtin_amdgcn_mfma_f32_16x16x32_bf16(
                        af[mt], bf[nt], acc[mt][nt], 0, 0, 0);
        }
        __syncthreads();
    }

    const int base_row = bm * 128 + wm + fg * 4;
    const int base_col = bn * 128 + wn + fr;
#pragma unroll
    for (int mt = 0; mt < 4; mt++) {
#pragma unroll
        for (int nt = 0; nt < 4; nt++) {
            int col = base_col + nt * 16;
            float bv = bias[col];
#pragma unroll
            for (int e = 0; e < 4; e++) {
                int row = base_row + mt * 16 + e;
                float val = (acc[mt][nt][e] + bv) * scale;
                if (mode == 2) {
                    ((float*)out)[(size_t)row * HIDDEN + col] = val;
                } else {
                    int b = row >> 11, s = row & (SEQ - 1);
                    int h = col >> 6, d = col & (DK - 1);
                    size_t idx;
                    if (mode == 0)
                        idx = ((size_t)(b * HEADS + h) * SEQ + s) * DK + d;
                    else
                        idx = ((size_t)(b * HEADS + h) * DK + d) * SEQ + s;
                    ((unsigned short*)out)[idx] = f2bf(val);
                }
            }
        }
    }
}

__global__ __launch_bounds__(256) void gemm_qkv(
    const unsigned short* __restrict__ qbf, const unsigned short* __restrict__ kbf,
    const unsigned short* __restrict__ vbf, const unsigned short* __restrict__ wq,
    const unsigned short* __restrict__ wk, const unsigned short* __restrict__ wv,
    const float* __restrict__ bq, const float* __restrict__ bk,
    const float* __restrict__ bv, unsigned short* __restrict__ qh,
    unsigned short* __restrict__ kh, unsigned short* __restrict__ vt) {
    int z = blockIdx.z;
    const unsigned short* A = (z == 0) ? qbf : (z == 1) ? kbf : vbf;
    const unsigned short* W = (z == 0) ? wq : (z == 1) ? wk : wv;
    const float* bias       = (z == 0) ? bq : (z == 1) ? bk : bv;
    unsigned short* out     = (z == 0) ? qh : (z == 1) ? kh : vt;
    gemm_body(A, W, bias, out, (z == 2) ? 1 : 0, (z == 0) ? QSCALE : 1.0f);
}

__global__ __launch_bounds__(256) void gemm_out(const unsigned short* __restrict__ ctx,
                                                const unsigned short* __restrict__ wo,
                                                const float* __restrict__ bo,
                                                float* __restrict__ out) {
    gemm_body(ctx, wo, bo, out, 2, 1.0f);
}

// ---------------- flash attention v5: dual q-stream per wave ----------------
// grid 256 (XCD-chunked: by=g>>3 head 0..31, bx=g&7 256-row q block). block 512 = 8 waves.
// wave w: qsub=w&3, split=w>>2. Each wave owns TWO 32-row q groups:
//   q0a = bx*256 + qsub*32, q0b = q0a + 128  -> K/V ds_reads shared across both streams
//   (LDS reads per MFMA halved vs v4; per-CU LDS traffic & conflicts halved via grid/2).
// K/V staged per block exactly as v4 (both splits, double-buffered, XOR-swizzled).
__global__ __launch_bounds__(512, 2) void attn_kernel(const unsigned short* __restrict__ qh,
                                                      const unsigned short* __restrict__ kh,
                                                      const unsigned short* __restrict__ vt,
                                                      unsigned short* __restrict__ ctx) {
    const int t = threadIdx.x, lane = t & 63, w = t >> 6;
    const int lo = lane & 31, hi = lane >> 5;
    const int qsub = w & 3, split = w >> 2;
    const int id = blockIdx.x;
    const int g  = (id & 7) * 32 + (id >> 3);   // XCD-chunked: 4 heads per XCD
    const int by = g >> 3;                       // head-batch 0..31
    const int bx = g & 7;                        // 256-row q block 0..7
    const size_t hb = (size_t)by * (SEQ * DK);
    const int q0a = bx * 256 + qsub * 32;
    const int q0b = q0a + 128;

    struct KV { unsigned short K[2][2][64 * 64]; unsigned short V[2][2][64 * 64]; };
    struct MG { float Lo[4][2][32][64]; float Lml[4][2][2][64]; };
    __shared__ union SMem { KV kv; MG mg; } sm;

    // staging setup (identical to v4): 32 units of 8 rows x 128B
    const unsigned short* sp[4];
    unsigned short* dpK[4];
    int sstr[4];
#pragma unroll
    for (int i = 0; i < 4; ++i) {
        int u   = w * 4 + i;
        int isV = u >> 4;
        int ssp = (u >> 3) & 1;
        int r0  = (u & 7) * 8;
        int rl  = r0 + (lane >> 3);
        int cs  = ((lane & 7) ^ ((lane >> 3) & 7)) * 8;
        if (!isV) {
            sp[i]   = kh + hb + (size_t)(ssp * 1024 + rl) * DK + cs;
            sstr[i] = 64 * DK;
            dpK[i]  = &sm.kv.K[0][ssp][r0 * 64];
        } else {
            sp[i]   = vt + hb + (size_t)rl * SEQ + ssp * 1024 + cs;
            sstr[i] = 64;
            dpK[i]  = &sm.kv.V[0][ssp][r0 * 64];
        }
    }
    const int bufoff = 2 * 64 * 64;

    bf16x8 qfA[4], qfB[4];
#pragma unroll
    for (int tl = 0; tl < 4; ++tl) {
        qfA[tl] = ld_bf8(&qh[hb + (size_t)(q0a + lo) * DK + tl * 16 + hi * 8]);
        qfB[tl] = ld_bf8(&qh[hb + (size_t)(q0b + lo) * DK + tl * 16 + hi * 8]);
    }

    f32x16 o0a, o1a, o0b, o1b;
#pragma unroll
    for (int e = 0; e < 16; ++e) { o0a[e] = 0.f; o1a[e] = 0.f; o0b[e] = 0.f; o1b[e] = 0.f; }
    float mA = -3.0e38f, lA = 0.f, mB = -3.0e38f, lB = 0.f;

#pragma unroll
    for (int i = 0; i < 4; ++i) { gload16(sp[i], dpK[i]); sp[i] += sstr[i]; }
    __syncthreads();

    const int xr = lo & 7;

    for (int it = 0; it < 16; ++it) {
        const unsigned short* Kb = &sm.kv.K[it & 1][split][0];
        const unsigned short* Vb = &sm.kv.V[it & 1][split][0];
        if (it < 15) {
#pragma unroll
            for (int i = 0; i < 4; ++i) {
                unsigned short* d = dpK[i] + ((it & 1) ? 0 : bufoff);
                gload16(sp[i], d);
                sp[i] += sstr[i];
            }
        }
        // QK^T: shared K-frags feed both q streams (4 MFMAs per tl)
        f32x16 sAa, sBa, sAb, sBb;
#pragma unroll
        for (int e = 0; e < 16; ++e) { sAa[e] = 0.f; sBa[e] = 0.f; sAb[e] = 0.f; sBb[e] = 0.f; }
        __builtin_amdgcn_s_setprio(1);
#pragma unroll
        for (int tl = 0; tl < 4; ++tl) {
            int c = 2 * tl + hi;
            bf16x8 kfA = ld_bf8(&Kb[lo * 64 + ((c ^ xr) * 8)]);
            bf16x8 kfB = ld_bf8(&Kb[(32 + lo) * 64 + ((c ^ xr) * 8)]);
            sAa = __builtin_amdgcn_mfma_f32_32x32x16_bf16(kfA, qfA[tl], sAa, 0, 0, 0);
            sBa = __builtin_amdgcn_mfma_f32_32x32x16_bf16(kfB, qfA[tl], sBa, 0, 0, 0);
            sAb = __builtin_amdgcn_mfma_f32_32x32x16_bf16(kfA, qfB[tl], sAb, 0, 0, 0);
            sBb = __builtin_amdgcn_mfma_f32_32x32x16_bf16(kfB, qfB[tl], sBb, 0, 0, 0);
        }
        __builtin_amdgcn_s_setprio(0);
        // ---- softmax A ----
        float pm = fmaxf(tmax16(sAa), tmax16(sBa));
        pm = fmaxf(pm, __shfl_xor(pm, 32));
        if (__any(pm > mA + 8.f)) {
            float mn  = fmaxf(mA, pm);
            float fac = __builtin_amdgcn_exp2f(mA - mn);
            mA = mn;
            lA *= fac;
#pragma unroll
            for (int e = 0; e < 16; ++e) { o0a[e] *= fac; o1a[e] *= fac; }
        }
#pragma unroll
        for (int e = 0; e < 16; ++e) {
            sAa[e] = __builtin_amdgcn_exp2f(sAa[e] - mA);
            sBa[e] = __builtin_amdgcn_exp2f(sBa[e] - mA);
        }
        {
            float sum = tsum16(sAa) + tsum16(sBa);
            sum += __shfl_xor(sum, 32);
            lA += sum;
        }
        // pack A
        uint32_t pA[8], pB[8];
#pragma unroll
        for (int i = 0; i < 8; ++i) {
            pA[i] = pkbf(sAa[2 * i], sAa[2 * i + 1]);
            pB[i] = pkbf(sBa[2 * i], sBa[2 * i + 1]);
        }
        asm volatile("v_permlane32_swap_b32 %0, %1" : "+v"(pA[0]), "+v"(pA[2]));
        asm volatile("v_permlane32_swap_b32 %0, %1" : "+v"(pA[1]), "+v"(pA[3]));
        asm volatile("v_permlane32_swap_b32 %0, %1" : "+v"(pA[4]), "+v"(pA[6]));
        asm volatile("v_permlane32_swap_b32 %0, %1" : "+v"(pA[5]), "+v"(pA[7]));
        asm volatile("v_permlane32_swap_b32 %0, %1" : "+v"(pB[0]), "+v"(pB[2]));
        asm volatile("v_permlane32_swap_b32 %0, %1" : "+v"(pB[1]), "+v"(pB[3]));
        asm volatile("v_permlane32_swap_b32 %0, %1" : "+v"(pB[4]), "+v"(pB[6]));
        asm volatile("v_permlane32_swap_b32 %0, %1" : "+v"(pB[5]), "+v"(pB[7]));
        union { uint32_t u[4]; bf16x8 v; } f0a, f1a, f2a, f3a;
        f0a.u[0] = pA[0]; f0a.u[1] = pA[1]; f0a.u[2] = pA[2]; f0a.u[3] = pA[3];
        f1a.u[0] = pA[4]; f1a.u[1] = pA[5]; f1a.u[2] = pA[6]; f1a.u[3] = pA[7];
        f2a.u[0] = pB[0]; f2a.u[1] = pB[1]; f2a.u[2] = pB[2]; f2a.u[3] = pB[3];
        f3a.u[0] = pB[4]; f3a.u[1] = pB[5]; f3a.u[2] = pB[6]; f3a.u[3] = pB[7];
        // V loads (shared by both streams)
        bf16x8 v00 = ld_bf8(&Vb[lo * 64 + (((0 + hi) ^ xr) * 8)]);
        bf16x8 v01 = ld_bf8(&Vb[lo * 64 + (((2 + hi) ^ xr) * 8)]);
        bf16x8 v02 = ld_bf8(&Vb[lo * 64 + (((4 + hi) ^ xr) * 8)]);
        bf16x8 v03 = ld_bf8(&Vb[lo * 64 + (((6 + hi) ^ xr) * 8)]);
        bf16x8 v10 = ld_bf8(&Vb[(32 + lo) * 64 + (((0 + hi) ^ xr) * 8)]);
        bf16x8 v11 = ld_bf8(&Vb[(32 + lo) * 64 + (((2 + hi) ^ xr) * 8)]);
        bf16x8 v12 = ld_bf8(&Vb[(32 + lo) * 64 + (((4 + hi) ^ xr) * 8)]);
        bf16x8 v13 = ld_bf8(&Vb[(32 + lo) * 64 + (((6 + hi) ^ xr) * 8)]);
        // PV-A
        __builtin_amdgcn_s_setprio(1);
        o0a = __builtin_amdgcn_mfma_f32_32x32x16_bf16(v00, f0a.v, o0a, 0, 0, 0);
        o0a = __builtin_amdgcn_mfma_f32_32x32x16_bf16(v01, f1a.v, o0a, 0, 0, 0);
        o0a = __builtin_amdgcn_mfma_f32_32x32x16_bf16(v02, f2a.v, o0a, 0, 0, 0);
        o0a = __builtin_amdgcn_mfma_f32_32x32x16_bf16(v03, f3a.v, o0a, 0, 0, 0);
        o1a = __builtin_amdgcn_mfma_f32_32x32x16_bf16(v10, f0a.v, o1a, 0, 0, 0);
        o1a = __builtin_amdgcn_mfma_f32_32x32x16_bf16(v11, f1a.v, o1a, 0, 0, 0);
        o1a = __builtin_amdgcn_mfma_f32_32x32x16_bf16(v12, f2a.v, o1a, 0, 0, 0);
        o1a = __builtin_amdgcn_mfma_f32_32x32x16_bf16(v13, f3a.v, o1a, 0, 0, 0);
        __builtin_amdgcn_s_setprio(0);
        // ---- softmax B (VALU overlaps PV-A's MFMA on the other wave) ----
        float qm = fmaxf(tmax16(sAb), tmax16(sBb));
        qm = fmaxf(qm, __shfl_xor(qm, 32));
        if (__any(qm > mB + 8.f)) {
            float mn  = fmaxf(mB, qm);
            float fac = __builtin_amdgcn_exp2f(mB - mn);
            mB = mn;
            lB *= fac;
#pragma unroll
            for (int e = 0; e < 16; ++e) { o0b[e] *= fac; o1b[e] *= fac; }
        }
#pragma unroll
        for (int e = 0; e < 16; ++e) {
            sAb[e] = __builtin_amdgcn_exp2f(sAb[e] - mB);
            sBb[e] = __builtin_amdgcn_exp2f(sBb[e] - mB);
        }
        {
            float sum = tsum16(sAb) + tsum16(sBb);
            sum += __shfl_xor(sum, 32);
            lB += sum;
        }
#pragma unroll
        for (int i = 0; i < 8; ++i) {
            pA[i] = pkbf(sAb[2 * i], sAb[2 * i + 1]);
            pB[i] = pkbf(sBb[2 * i], sBb[2 * i + 1]);
        }
        asm volatile("v_permlane32_swap_b32 %0, %1" : "+v"(pA[0]), "+v"(pA[2]));
        asm volatile("v_permlane32_swap_b32 %0, %1" : "+v"(pA[1]), "+v"(pA[3]));
        asm volatile("v_permlane32_swap_b32 %0, %1" : "+v"(pA[4]), "+v"(pA[6]));
        asm volatile("v_permlane32_swap_b32 %0, %1" : "+v"(pA[5]), "+v"(pA[7]));
        asm volatile("v_permlane32_swap_b32 %0, %1" : "+v"(pB[0]), "+v"(pB[2]));
        asm volatile("v_permlane32_swap_b32 %0, %1" : "+v"(pB[1]), "+v"(pB[3]));
        asm volatile("v_permlane32_swap_b32 %0, %1" : "+v"(pB[4]), "+v"(pB[6]));
        asm volatile("v_permlane32_swap_b32 %0, %1" : "+v"(pB[5]), "+v"(pB[7]));
        union { uint32_t u[4]; bf16x8 v; } f0b, f1b, f2b, f3b;
        f0b.u[0] = pA[0]; f0b.u[1] = pA[1]; f0b.u[2] = pA[2]; f0b.u[3] = pA[3];
        f1b.u[0] = pA[4]; f1b.u[1] = pA[5]; f1b.u[2] = pA[6]; f1b.u[3] = pA[7];
        f2b.u[0] = pB[0]; f2b.u[1] = pB[1]; f2b.u[2] = pB[2]; f2b.u[3] = pB[3];
        f3b.u[0] = pB[4]; f3b.u[1] = pB[5]; f3b.u[2] = pB[6]; f3b.u[3] = pB[7];
        // PV-B (V-frags reused)
        __builtin_amdgcn_s_setprio(1);
        o0b = __builtin_amdgcn_mfma_f32_32x32x16_bf16(v00, f0b.v, o0b, 0, 0, 0);
        o0b = __builtin_amdgcn_mfma_f32_32x32x16_bf16(v01, f1b.v, o0b, 0, 0, 0);
        o0b = __builtin_amdgcn_mfma_f32_32x32x16_bf16(v02, f2b.v, o0b, 0, 0, 0);
        o0b = __builtin_amdgcn_mfma_f32_32x32x16_bf16(v03, f3b.v, o0b, 0, 0, 0);
        o1b = __builtin_amdgcn_mfma_f32_32x32x16_bf16(v10, f0b.v, o1b, 0, 0, 0);
        o1b = __builtin_amdgcn_mfma_f32_32x32x16_bf16(v11, f1b.v, o1b, 0, 0, 0);
        o1b = __builtin_amdgcn_mfma_f32_32x32x16_bf16(v12, f2b.v, o1b, 0, 0, 0);
        o1b = __builtin_amdgcn_mfma_f32_32x32x16_bf16(v13, f3b.v, o1b, 0, 0, 0);
        __builtin_amdgcn_s_setprio(0);
        __syncthreads();
    }

    // split-1 waves publish both streams' partials
    if (split == 1) {
#pragma unroll
        for (int e = 0; e < 16; ++e) {
            sm.mg.Lo[qsub][0][e][lane]      = o0a[e];
            sm.mg.Lo[qsub][0][16 + e][lane] = o1a[e];
            sm.mg.Lo[qsub][1][e][lane]      = o0b[e];
            sm.mg.Lo[qsub][1][16 + e][lane] = o1b[e];
        }
        sm.mg.Lml[qsub][0][0][lane] = mA;
        sm.mg.Lml[qsub][0][1][lane] = lA;
        sm.mg.Lml[qsub][1][0][lane] = mB;
        sm.mg.Lml[qsub][1][1][lane] = lB;
    }
    __syncthreads();
    if (split == 0) {
        const int b = by >> 4, hd = by & 15;
        // ---- stream A ----
        {
            float m2 = sm.mg.Lml[qsub][0][0][lane];
            float l2 = sm.mg.Lml[qsub][0][1][lane];
            float M  = fmaxf(mA, m2);
            float a0 = __builtin_amdgcn_exp2f(mA - M);
            float a1 = __builtin_amdgcn_exp2f(m2 - M);
            float rl = __builtin_amdgcn_rcpf(a0 * lA + a1 * l2);
            unsigned short* orow = ctx + ((size_t)(b * SEQ + q0a + lo)) * HIDDEN + hd * 64;
#pragma unroll
            for (int dt = 0; dt < 2; ++dt) {
#pragma unroll
                for (int gq = 0; gq < 4; ++gq) {
                    union { unsigned short us[4]; uint2 v; } pk;
#pragma unroll
                    for (int c = 0; c < 4; ++c) {
                        int e = gq * 4 + c;
                        float own = dt ? o1a[e] : o0a[e];
                        float oth = sm.mg.Lo[qsub][0][dt * 16 + e][lane];
                        pk.us[c] = f2bf((own * a0 + oth * a1) * rl);
                    }
                    *reinterpret_cast<uint2*>(orow + dt * 32 + gq * 8 + hi * 4) = pk.v;
                }
            }
        }
        // ---- stream B ----
        {
            float m2 = sm.mg.Lml[qsub][1][0][lane];
            float l2 = sm.mg.Lml[qsub][1][1][lane];
            float M  = fmaxf(mB, m2);
            float a0 = __builtin_amdgcn_exp2f(mB - M);
            float a1 = __builtin_amdgcn_exp2f(m2 - M);
            float rl = __builtin_amdgcn_rcpf(a0 * lB + a1 * l2);
            unsigned short* orow = ctx + ((size_t)(b * SEQ + q0b + lo)) * HIDDEN + hd * 64;
#pragma unroll
            for (int dt = 0; dt < 2; ++dt) {
#pragma unroll
                for (int gq = 0; gq < 4; ++gq) {
                    union { unsigned short us[4]; uint2 v; } pk;
#pragma unroll
                    for (int c = 0; c < 4; ++c) {
                        int e = gq * 4 + c;
                        float own = dt ? o1b[e] : o0b[e];
                        float oth = sm.mg.Lo[qsub][1][dt * 16 + e][lane];
                        pk.us[c] = f2bf((own * a0 + oth * a1) * rl);
                    }
                    *reinterpret_cast<uint2*>(orow + dt * 32 + gq * 8 + hi * 4) = pk.v;
                }
            }
        }
    }
}

// ---------------- launch ----------------
extern "C" void kernel_launch(void* const* d_in, const int* in_sizes, int n_in,
                              void* d_out, int out_size, void* d_ws, size_t ws_size,
                              hipStream_t stream) {
    const float* q  = (const float*)d_in[0];
    const float* k  = (const float*)d_in[1];
    const float* v  = (const float*)d_in[2];
    const float* Wq = (const float*)d_in[3];
    const float* bq = (const float*)d_in[4];
    const float* Wk = (const float*)d_in[5];
    const float* bk = (const float*)d_in[6];
    const float* Wv = (const float*)d_in[7];
    const float* bv = (const float*)d_in[8];
    const float* Wo = (const float*)d_in[9];
    const float* bo = (const float*)d_in[10];

    unsigned short* qbf = (unsigned short*)d_ws;
    unsigned short* kbf = qbf + (size_t)MTOT * HIDDEN;
    unsigned short* vbf = kbf + (size_t)MTOT * HIDDEN;
    unsigned short* wqb = vbf + (size_t)MTOT * HIDDEN;
    unsigned short* wkb = wqb + (size_t)HIDDEN * HIDDEN;
    unsigned short* wvb = wkb + (size_t)HIDDEN * HIDDEN;
    unsigned short* wob = wvb + (size_t)HIDDEN * HIDDEN;
    unsigned short* qh  = wob + (size_t)HIDDEN * HIDDEN;
    unsigned short* kh  = qh + (size_t)MTOT * HIDDEN;
    unsigned short* vt  = kh + (size_t)MTOT * HIDDEN;
    unsigned short* ctx = vt + (size_t)MTOT * HIDDEN;

    const int nAct8 = MTOT * HIDDEN / 8;    // 524288
    const int nW8   = HIDDEN * HIDDEN / 8;  // 131072

    Cvt7 ca;
    ca.s[0] = q;  ca.d[0] = qbf; ca.n8[0] = nAct8;
    ca.s[1] = k;  ca.d[1] = kbf; ca.n8[1] = nAct8;
    ca.s[2] = v;  ca.d[2] = vbf; ca.n8[2] = nAct8;
    ca.s[3] = Wq; ca.d[3] = wqb; ca.n8[3] = nW8;
    ca.s[4] = Wk; ca.d[4] = wkb; ca.n8[4] = nW8;
    ca.s[5] = Wv; ca.d[5] = wvb; ca.n8[5] = nW8;
    ca.s[6] = Wo; ca.d[6] = wob; ca.n8[6] = nW8;
    cvt_all<<<dim3(nAct8 / 256, 7), dim3(256), 0, stream>>>(ca);

    gemm_qkv<<<dim3(HIDDEN / 128, MTOT / 128, 3), dim3(256), 0, stream>>>(
        qbf, kbf, vbf, wqb, wkb, wvb, bq, bk, bv, qh, kh, vt);

    attn_kernel<<<dim3(256), dim3(512), 0, stream>>>(qh, kh, vt, ctx);

    gemm_out<<<dim3(HIDDEN / 128, MTOT / 128), dim3(256), 0, stream>>>(
        ctx, wob, bo, (float*)d_out);
}